// Round 8
// baseline (652.126 us; speedup 1.0000x reference)
//
#include <hip/hip_runtime.h>
#include <hip/hip_bf16.h>
#include <math.h>

typedef __hip_bfloat16 bf16;
typedef __attribute__((ext_vector_type(8))) short bf16x8;
typedef __attribute__((ext_vector_type(4))) float f32x4;

#define DEVI __device__ __forceinline__

// ---------- constants ----------
#define C_ 512
#define NH_ 4
#define NTOK 11520          // B*T*H*W
#define NKEY 1680           // 360 local + 960 rolled + 360 pooled
#define NRK 120
#define FFN_ 1960
#define ZROW (NTOK + 256)   // zeroed key row for invalid slots

// ---------- helpers ----------
DEVI float ldf(const bf16* p) { return __bfloat162float(*p); }
DEVI float ldf(const float* p) { return *p; }
DEVI void stw(bf16* p, float v) { *p = __float2bfloat16(v); }
DEVI void stw(float* p, float v) { *p = v; }
DEVI unsigned short f2bs(float f) { bf16 h = __float2bfloat16(f); return *(unsigned short*)&h; }
DEVI unsigned pk2f(float a, float b) {
  return (unsigned)f2bs(a) | ((unsigned)f2bs(b) << 16);
}

// dtype-dispatched scalar load: DT=0 bf16, DT=1 f32
template <int DT> DEVI float ldw(const void* p, size_t i) {
  if (DT == 0) return __bfloat162float(((const bf16*)p)[i]);
  else         return ((const float*)p)[i];
}

// async global->LDS, 16B per lane; lptr is wave-uniform base (HW adds lane*16)
DEVI void gload_lds16(const void* g, void* l) {
  __builtin_amdgcn_global_load_lds(
      (const __attribute__((address_space(1))) void*)g,
      (__attribute__((address_space(3))) void*)l, 16, 0, 0);
}

// ---------- K_init: dtype detect + valid-index table + zero-row ----------
__global__ void k_init(const void* __restrict__ g1, int* __restrict__ flag,
                       int* __restrict__ table, bf16* __restrict__ zp) {
  if (blockIdx.x == 0) {
    if (threadIdx.x == 0) {
      const unsigned short* p = (const unsigned short*)g1;
      *flag = (p[0] == 0x3F80u) ? 0 : 1;
      int cnt = 0;
      for (int pq = 0; pq < 4; pq++)
        for (int wi = 0; wi < 5; wi++)
          for (int wj = 0; wj < 9; wj++) {
            bool invalid;
            if (pq == 0)      invalid = (wi < 3) && (wj < 5);
            else if (pq == 1) invalid = (wi < 3) && (wj >= 4);
            else if (pq == 2) invalid = (wi >= 2) && (wj < 5);
            else              invalid = (wi >= 2) && (wj >= 4);
            if (!invalid) table[cnt++] = pq * 45 + wi * 9 + wj;
          }
    }
  } else {
    zp[(blockIdx.x - 1) * 256 + threadIdx.x] = __float2bfloat16(0.f);
  }
}

// ---------- K0b: per-window key-source table ksrc[32][1680] ----------
// values: token row (<NTOK) for local/rolled, NTOK+pidx for pooled, -1 invalid
__global__ void k_ksrc(const int* __restrict__ vtab, int* __restrict__ ksrc) {
  int idx = blockIdx.x * 256 + threadIdx.x;
  if (idx >= 32 * NKEY) return;
  int w = idx / NKEY, j = idx % NKEY;
  int b = w >> 4, nh = (w >> 2) & 3, nw = w & 3;
  int val;
  if (j < 360) {
    int t = j / 45, pos = j % 45, wi = pos / 9, wj2 = pos % 9;
    val = ((b * 8 + t) * 20 + nh * 5 + wi) * 36 + nw * 9 + wj2;
  } else if (j < 1320) {
    int jj = j - 360;
    int t = jj / 120, r = jj % 120;
    int id = vtab[r];
    int p = id / 45, pos = id % 45, wi = pos / 9, wj2 = pos % 9;
    int sh = (p < 2) ? -2 : 2;
    int sw = (p & 1) ? 4 : -4;
    int hh = nh * 5 + wi - sh;
    if (hh < 0) hh += 20; else if (hh >= 20) hh -= 20;
    int ww2 = nw * 9 + wj2 - sw;
    if (ww2 < 0) ww2 += 36; else if (ww2 >= 36) ww2 -= 36;
    val = ((b * 8 + t) * 20 + hh) * 36 + ww2;
  } else {
    int jj = j - 1320;
    int t = jj / 45, kidx = jj % 45, ki = kidx / 9, kj = kidx % 9;
    int snh = nh + ki - 2, snw = nw + kj - 4;
    if (snh < 0 || snh >= 4 || snw < 0 || snw >= 4) val = -1;
    else val = NTOK + (b * 8 + t) * 16 + snh * 4 + snw;
  }
  ksrc[idx] = val;
}

// ---------- weight convert+transpose (LDS-tiled, both sides coalesced) ----------
// out[n][k] = in[k][n], bf16, zero-pad n>=N.  grid: (ceil(Npad/64), ceil(K/64))
template <int DT>
DEVI void wcvt_body(const void* in, bf16* out, int K, int N, int Npad) {
  __shared__ float t[64][65];
  const int n0 = blockIdx.x * 64;
  const int k0 = blockIdx.y * 64;
  const int tx = threadIdx.x & 63, tg = threadIdx.x >> 6;
#pragma unroll
  for (int r = 0; r < 16; r++) {
    int k = k0 + r * 4 + tg;
    int nn = n0 + tx;
    float v = (k < K && nn < N) ? ldw<DT>(in, (size_t)k * N + nn) : 0.f;
    t[r * 4 + tg][tx] = v;
  }
  __syncthreads();
#pragma unroll
  for (int r = 0; r < 16; r++) {
    int nn = n0 + r * 4 + tg;
    int k = k0 + tx;
    if (nn < Npad && k < K)
      out[(size_t)nn * K + k] = __float2bfloat16(t[tx][r * 4 + tg]);
  }
}
__global__ void k_wcvt(const int* __restrict__ dflag, const void* __restrict__ in,
                       bf16* __restrict__ out, int K, int N, int Npad) {
  if (*dflag == 0) wcvt_body<0>(in, out, K, N, Npad);
  else             wcvt_body<1>(in, out, K, N, Npad);
}

// ---------- bias convert -> f32 (all four biases in one launch) ----------
// grid 18 blocks: [0,6)=bqkv(1536) [6,8)=bproj(512) [8,16)=bf1(1960 pad) [16,18)=bf2(512)
__global__ void k_bcvt4(const int* __restrict__ dflag,
                        const void* __restrict__ b0, float* __restrict__ o0,
                        const void* __restrict__ b1, float* __restrict__ o1,
                        const void* __restrict__ b2, float* __restrict__ o2,
                        const void* __restrict__ b3, float* __restrict__ o3) {
  int dt = *dflag;
  int bx = blockIdx.x;
  const void* src; float* dst; int n, i;
  if (bx < 6)       { src = b0; dst = o0; n = 1536; i = bx * 256 + threadIdx.x; }
  else if (bx < 8)  { src = b1; dst = o1; n = 512;  i = (bx - 6) * 256 + threadIdx.x; }
  else if (bx < 16) { src = b2; dst = o2; n = FFN_; i = (bx - 8) * 256 + threadIdx.x; }
  else              { src = b3; dst = o3; n = 512;  i = (bx - 16) * 256 + threadIdx.x; }
  if (i < n) dst[i] = (dt == 0) ? ldw<0>(src, i) : ldw<1>(src, i);
}

// ---------- LayerNorm over C=512 ----------
template <int DTIN, int DTP>
DEVI void ln_body(const void* xin, const void* g, const void* be, bf16* out) {
  const int tok = blockIdx.x;
  const int tid = threadIdx.x;
  const size_t base = (size_t)tok * C_;
  float v0 = ldw<DTIN>(xin, base + tid);
  float v1 = ldw<DTIN>(xin, base + tid + 256);
  float s = v0 + v1, ss = v0 * v0 + v1 * v1;
#pragma unroll
  for (int o = 32; o; o >>= 1) { s += __shfl_xor(s, o); ss += __shfl_xor(ss, o); }
  __shared__ float sh[10];
  const int lane = tid & 63, wv = tid >> 6;
  if (lane == 0) { sh[wv] = s; sh[4 + wv] = ss; }
  __syncthreads();
  if (tid == 0) {
    float a = sh[0] + sh[1] + sh[2] + sh[3];
    float q = sh[4] + sh[5] + sh[6] + sh[7];
    float mu = a * (1.0f / C_);
    float var = q * (1.0f / C_) - mu * mu;
    sh[8] = mu; sh[9] = rsqrtf(fmaxf(var, 0.f) + 1e-5f);
  }
  __syncthreads();
  float mu = sh[8], inv = sh[9];
  stw(out + base + tid,
      (v0 - mu) * inv * ldw<DTP>(g, tid) + ldw<DTP>(be, tid));
  stw(out + base + tid + 256,
      (v1 - mu) * inv * ldw<DTP>(g, tid + 256) + ldw<DTP>(be, tid + 256));
}
// mode 0: input dtype follows dflag (LN1); mode 1: input always f32 (LN2)
__global__ void k_ln(const int* __restrict__ dflag, int mode,
                     const void* __restrict__ xin, const void* __restrict__ g,
                     const void* __restrict__ be, bf16* __restrict__ out) {
  int dt = *dflag;
  if (mode == 0) {
    if (dt == 0) ln_body<0, 0>(xin, g, be, out);
    else         ln_body<1, 1>(xin, g, be, out);
  } else {
    if (dt == 0) ln_body<1, 0>(xin, g, be, out);
    else         ln_body<1, 1>(xin, g, be, out);
  }
}

// ---------- window pooling ----------
template <int DT>
DEVI void pool_body(const bf16* xn, const void* wpool, const void* bpool,
                    float* pooled) {
  int idx = blockIdx.x * blockDim.x + threadIdx.x;
  if (idx >= 256 * C_) return;
  int c = idx & (C_ - 1);
  int fw = idx >> 9;
  int nw = fw & 3, nh = (fw >> 2) & 3;
  int bt = fw >> 4;
  float acc = ldw<DT>(bpool, 0);
  for (int wi = 0; wi < 5; wi++) {
    int hh = nh * 5 + wi;
    const bf16* base = xn + (((size_t)(bt * 20 + hh)) * 36 + nw * 9) * C_ + c;
    for (int wj = 0; wj < 9; wj++)
      acc += __bfloat162float(base[(size_t)wj * C_]) * ldw<DT>(wpool, wi * 9 + wj);
  }
  pooled[idx] = acc;
}
__global__ void k_pool(const int* __restrict__ dflag, const bf16* __restrict__ xn,
                       const void* __restrict__ wpool, const void* __restrict__ bpool,
                       float* __restrict__ pooled) {
  if (*dflag == 0) pool_body<0>(xn, wpool, bpool, pooled);
  else             pool_body<1>(xn, wpool, bpool, pooled);
}

// ---------- small GEMM pooled(f32) @ wqkv + bqkv -> qkvp_b (bf16, stride 1536) ----------
// grid (6, 32): n0 = bx*256, m0 = by*8; A tile in LDS, B reads coalesced.
template <int DT>
DEVI void gemm_small_body(const float* A, const void* Bw, const void* bias,
                          bf16* Cc) {
  __shared__ float As[8][512];
  const int n = blockIdx.x * 256 + threadIdx.x;
  const int m0 = blockIdx.y * 8;
  for (int i = threadIdx.x; i < 8 * 512; i += 256)
    As[i >> 9][i & 511] = A[(size_t)(m0 + (i >> 9)) * 512 + (i & 511)];
  __syncthreads();
  float acc[8];
  float bv = ldw<DT>(bias, n);
#pragma unroll
  for (int mm = 0; mm < 8; mm++) acc[mm] = bv;
  for (int k = 0; k < 512; k++) {
    float b = ldw<DT>(Bw, (size_t)k * 1536 + n);
#pragma unroll
    for (int mm = 0; mm < 8; mm++) acc[mm] += As[mm][k] * b;
  }
#pragma unroll
  for (int mm = 0; mm < 8; mm++)
    Cc[(size_t)(m0 + mm) * 1536 + n] = __float2bfloat16(acc[mm]);
}
__global__ void k_gemm_small(const int* __restrict__ dflag, const float* __restrict__ A,
                             const void* __restrict__ Bw, const void* __restrict__ bias,
                             bf16* __restrict__ Cc) {
  if (*dflag == 0) gemm_small_body<0>(A, Bw, bias, Cc);
  else             gemm_small_body<1>(A, Bw, bias, Cc);
}

// ---------- MFMA GEMM: out[M][N] = A[M][K](bf16) @ Bt[N][K]^T(bf16) + bias(f32) ----------
// BK=64 as two [128][32] chunks (keeps proven 64B-row LDS layout / bank behavior)
// -> one barrier pair per 64-k step (R7: -21us vs BK=32).
// XCD-bijective block swizzle (T1/m204): all grids have nwg%8==0; chunked remap
// keeps blocks sharing an A-panel on the same XCD -> panel L2-resident.
// RES=0: out bf16.  RES=1: out f32, resid dtype = *dflag.  RES=2: resid f32, out dtype = *dflag.
template <int RES>
__global__ __launch_bounds__(256) void k_gemm_m(const int* __restrict__ dflag,
                                                const bf16* __restrict__ A,
                                                const bf16* __restrict__ Bt,
                                                const float* __restrict__ bias,
                                                const void* __restrict__ resid,
                                                void* __restrict__ out,
                                                int M, int N, int K) {
  const int dt = dflag ? *dflag : 0;
  __shared__ __align__(16) unsigned short As[2][128 * 32];
  __shared__ __align__(16) unsigned short Bs[2][128 * 32];
  const int tid = threadIdx.x;
  const int lane = tid & 63, wid = tid >> 6;
  const int r15 = lane & 15, quad = lane >> 4;
  const int wm = wid >> 1, wn = wid & 1;
  // XCD-aware chunked swizzle (requires nwg % 8 == 0; all call sites satisfy)
  const int nbx = gridDim.x;
  const int lin = blockIdx.x + nbx * blockIdx.y;
  const int cpx = (nbx * gridDim.y) >> 3;
  const int swz = (lin & 7) * cpx + (lin >> 3);
  const int m0 = (swz / nbx) * 128, n0 = (swz % nbx) * 128;

  f32x4 acc[4][4];
#pragma unroll
  for (int i = 0; i < 4; i++)
#pragma unroll
    for (int j = 0; j < 4; j++)
#pragma unroll
      for (int e = 0; e < 4; e++) acc[i][j][e] = 0.f;

  const int lrow = lane >> 2, lcol = (lane & 3) * 8;

  for (int k0 = 0; k0 < K; k0 += 64) {
    int rem = K - k0;
    if (rem >= 64) {
      const bf16* ga = A + (size_t)(m0 + wid * 32 + lrow) * K + k0 + lcol;
      gload_lds16(ga, &As[0][wid * 1024]);
      gload_lds16(ga + (size_t)16 * K, &As[0][wid * 1024 + 512]);
      gload_lds16(ga + 32, &As[1][wid * 1024]);
      gload_lds16(ga + (size_t)16 * K + 32, &As[1][wid * 1024 + 512]);
      const bf16* gb = Bt + (size_t)(n0 + wid * 32 + lrow) * K + k0 + lcol;
      gload_lds16(gb, &Bs[0][wid * 1024]);
      gload_lds16(gb + (size_t)16 * K, &Bs[0][wid * 1024 + 512]);
      gload_lds16(gb + 32, &Bs[1][wid * 1024]);
      gload_lds16(gb + (size_t)16 * K + 32, &Bs[1][wid * 1024 + 512]);
    } else {
      // tail (rem multiple of 8, < 64): 32 rows x 64 cols per pass, 4 passes
      int r = tid >> 3, c = (tid & 7) * 8;
      uint4 z = make_uint4(0, 0, 0, 0);
      int h = c >> 5, cc = c & 31;
#pragma unroll
      for (int p = 0; p < 4; p++) {
        int row = r + p * 32;
        uint4 av = z, bv = z;
        if (c < rem) {
          av = *(const uint4*)(A + (size_t)(m0 + row) * K + k0 + c);
          bv = *(const uint4*)(Bt + (size_t)(n0 + row) * K + k0 + c);
        }
        *(uint4*)&As[h][row * 32 + cc] = av;
        *(uint4*)&Bs[h][row * 32 + cc] = bv;
      }
    }
    __syncthreads();

#pragma unroll
    for (int h = 0; h < 2; h++) {
      bf16x8 af[4], bfr[4];
#pragma unroll
      for (int mf = 0; mf < 4; mf++)
        af[mf] = *(const bf16x8*)&As[h][(wm * 64 + mf * 16 + r15) * 32 + quad * 8];
#pragma unroll
      for (int nf = 0; nf < 4; nf++)
        bfr[nf] = *(const bf16x8*)&Bs[h][(wn * 64 + nf * 16 + r15) * 32 + quad * 8];
#pragma unroll
      for (int mf = 0; mf < 4; mf++)
#pragma unroll
        for (int nf = 0; nf < 4; nf++)
          acc[mf][nf] = __builtin_amdgcn_mfma_f32_16x16x32_bf16(af[mf], bfr[nf],
                                                                acc[mf][nf], 0, 0, 0);
    }
    __syncthreads();
  }

#pragma unroll
  for (int nf = 0; nf < 4; nf++) {
    int n = n0 + wn * 64 + nf * 16 + r15;
    if (n >= N) continue;
    float bv = bias[n];
#pragma unroll
    for (int mf = 0; mf < 4; mf++) {
      int mb = m0 + wm * 64 + mf * 16 + quad * 4;
#pragma unroll
      for (int e = 0; e < 4; e++) {
        size_t off = (size_t)(mb + e) * N + n;
        float v = acc[mf][nf][e] + bv;
        if (RES == 1) v += (dt == 0) ? ldw<0>(resid, off) : ldw<1>(resid, off);
        else if (RES == 2) v += ((const float*)resid)[off];
        if (RES == 0) ((bf16*)out)[off] = __float2bfloat16(v);
        else if (RES == 1) ((float*)out)[off] = v;
        else {
          if (dt == 0) ((bf16*)out)[off] = __float2bfloat16(v);
          else         ((float*)out)[off] = v;
        }
      }
    }
  }
}

// ---------- MFMA flash attention (768 thr, 12 waves, K/V double-buffered) ----------
// grid: (32 windows, 2 qtiles, 4 heads) = 256 blocks (1 per CU)
// All key sources (local/rolled/pooled/invalid) are bf16 rows of stride 1536 in
// one array (pooled rows appended at NTOK, zero row at ZROW) -> branch-free staging.
// Staging registers are NAMED SCALARS (k0..k3 / v0,v1), not arrays: prevents the
// promote-alloca pass from spilling them to LDS (R2/R3 regression: LDS_Block_Size
// 107008->156160). Online softmax uses defer-max (THR=8, HK-style): skip the
// O-rescale + max update when no query row grew by >8 (R2 vs R3 evidence: -8us).
#define KT 64
#define KPAD 136
#define VPAD 72
__global__ __launch_bounds__(768) void k_attn_m(const bf16* __restrict__ qkv,
                                                const int* __restrict__ ksrc,
                                                bf16* __restrict__ ao) {
  __shared__ int ks_l[NKEY];
  __shared__ __align__(16) unsigned short ktl[2][KT * KPAD];    // K [key][dim]
  __shared__ __align__(16) unsigned short vtl[2][128 * VPAD];   // V^T [dim][key]
  __shared__ __align__(16) unsigned short ptl[12 * 16 * VPAD];  // P per wave [q][key]
  __shared__ float maskv[2][KT];

  const int tid = threadIdx.x;
  const int lane = tid & 63, wid = tid >> 6;   // wid 0..11
  const int r15 = lane & 15, quad = lane >> 4;
  const int w = blockIdx.x, qt = blockIdx.y, n = blockIdx.z;
  const int b = w >> 4, nh = (w >> 2) & 3, nw = w & 3;
  const unsigned short* qkvs = (const unsigned short*)qkv;

  for (int j = tid; j < NKEY; j += 768) ks_l[j] = ksrc[w * NKEY + j];

  // Q A-fragments (16 queries per wave), clamped for padding
  bf16x8 qf[4];
  {
    int qw = qt * 192 + wid * 16 + r15;
    int qc2 = qw < 360 ? qw : 359;
    int t = qc2 / 45, pos = qc2 % 45, wi = pos / 9, wj = pos % 9;
    int tok = ((b * 8 + t) * 20 + nh * 5 + wi) * 36 + nw * 9 + wj;
    const unsigned short* qp = qkvs + (size_t)tok * 1536 + n * 128 + quad * 8;
#pragma unroll
    for (int c = 0; c < 4; c++)
      qf[c] = *(const bf16x8*)(qp + c * 32);
  }

  f32x4 of[8];
#pragma unroll
  for (int nt = 0; nt < 8; nt++)
#pragma unroll
    for (int e = 0; e < 4; e++) of[nt][e] = 0.f;
  float m_[4], l_[4];   // l_ is a PER-LANE partial sum (reduced once at the end)
#pragma unroll
  for (int e = 0; e < 4; e++) { m_[e] = -1e30f; l_[e] = 0.f; }

  unsigned short* ptw = &ptl[wid * 16 * VPAD];

  // staging roles
  const bool isK = (wid < 4);
  const int kr = tid >> 2, kp = tid & 3;   // K role (tid < 256)
  const int vr = lane, vp8 = wid - 4;      // V role (wid >= 4)
  // named staging registers (NOT arrays -> guaranteed VGPRs)
  uint4 k0, k1, k2, k3, v0, v1;
  float mreg = -30000.f;
  // wave-invariant base offsets
  const unsigned short* kbase = qkvs + 512 + n * 128 + kp * 32;
  const unsigned short* vbase = qkvs + 1024 + n * 128 + vp8 * 16;

  auto load_tile = [&](int j0) {
    int cnt = NKEY - j0; if (cnt > KT) cnt = KT;
    if (isK) {
      int s0 = (kr < cnt) ? ks_l[j0 + kr] : -1;
      mreg = (s0 < 0) ? -30000.f : 0.f;
      int row = (s0 < 0) ? ZROW : s0;
      const uint4* kq = (const uint4*)(kbase + (size_t)row * 1536);
      k0 = kq[0]; k1 = kq[1]; k2 = kq[2]; k3 = kq[3];
    } else {
      int s1 = (vr < cnt) ? ks_l[j0 + vr] : -1;
      int row = (s1 < 0) ? ZROW : s1;
      const uint4* vq = (const uint4*)(vbase + (size_t)row * 1536);
      v0 = vq[0]; v1 = vq[1];
    }
  };

  auto store_tile = [&](int buf) {
    if (isK) {
      if (kp == 0) maskv[buf][kr] = mreg;
      unsigned short* kb = &ktl[buf][kr * KPAD + kp * 32];
      *(uint4*)&kb[0]  = k0;
      *(uint4*)&kb[8]  = k1;
      *(uint4*)&kb[16] = k2;
      *(uint4*)&kb[24] = k3;
    } else {
      unsigned short* vb = &vtl[buf][0];
      int d0 = vp8 * 16;
      vb[(d0 + 0) * VPAD + vr]  = (unsigned short)(v0.x & 0xFFFFu);
      vb[(d0 + 1) * VPAD + vr]  = (unsigned short)(v0.x >> 16);
      vb[(d0 + 2) * VPAD + vr]  = (unsigned short)(v0.y & 0xFFFFu);
      vb[(d0 + 3) * VPAD + vr]  = (unsigned short)(v0.y >> 16);
      vb[(d0 + 4) * VPAD + vr]  = (unsigned short)(v0.z & 0xFFFFu);
      vb[(d0 + 5) * VPAD + vr]  = (unsigned short)(v0.z >> 16);
      vb[(d0 + 6) * VPAD + vr]  = (unsigned short)(v0.w & 0xFFFFu);
      vb[(d0 + 7) * VPAD + vr]  = (unsigned short)(v0.w >> 16);
      vb[(d0 + 8) * VPAD + vr]  = (unsigned short)(v1.x & 0xFFFFu);
      vb[(d0 + 9) * VPAD + vr]  = (unsigned short)(v1.x >> 16);
      vb[(d0 + 10) * VPAD + vr] = (unsigned short)(v1.y & 0xFFFFu);
      vb[(d0 + 11) * VPAD + vr] = (unsigned short)(v1.y >> 16);
      vb[(d0 + 12) * VPAD + vr] = (unsigned short)(v1.z & 0xFFFFu);
      vb[(d0 + 13) * VPAD + vr] = (unsigned short)(v1.z >> 16);
      vb[(d0 + 14) * VPAD + vr] = (unsigned short)(v1.w & 0xFFFFu);
      vb[(d0 + 15) * VPAD + vr] = (unsigned short)(v1.w >> 16);
    }
  };

  __syncthreads();        // ks_l ready
  load_tile(0);
  store_tile(0);
  load_tile(KT);          // prefetch tile 1 into regs (NKEY > KT always)
  __syncthreads();        // buf 0 ready

  int cur = 0, j0 = 0;
  while (true) {
    int nxt = j0 + KT;
    if (nxt < NKEY) {
      store_tile(cur ^ 1);                        // regs (tile nxt) -> idle buffer
      if (nxt + KT < NKEY) load_tile(nxt + KT);   // prefetch tile nxt+KT
    }

    const unsigned short* ktc = &ktl[cur][0];
    const unsigned short* vtc = &vtl[cur][0];
    const float* mkc = maskv[cur];

    // ---- QK^T ----
    f32x4 sf[4];
#pragma unroll
    for (int ft = 0; ft < 4; ft++)
#pragma unroll
      for (int e = 0; e < 4; e++) sf[ft][e] = 0.f;
#pragma unroll
    for (int kc = 0; kc < 4; kc++) {
      bf16x8 a = qf[kc];
#pragma unroll
      for (int ft = 0; ft < 4; ft++) {
        bf16x8 bb = *(const bf16x8*)&ktc[(ft * 16 + r15) * KPAD + kc * 32 + quad * 8];
        sf[ft] = __builtin_amdgcn_mfma_f32_16x16x32_bf16(a, bb, sf[ft], 0, 0, 0);
      }
    }
    const float scl = 0.088388347648318447f;
#pragma unroll
    for (int ft = 0; ft < 4; ft++) {
      float mk = mkc[ft * 16 + r15];
#pragma unroll
      for (int e = 0; e < 4; e++) sf[ft][e] = sf[ft][e] * scl + mk;
    }
    // ---- online softmax (defer-max THR=8; lazy per-lane l partial) ----
    float tm[4];
#pragma unroll
    for (int e = 0; e < 4; e++) {
      float v = fmaxf(fmaxf(sf[0][e], sf[1][e]), fmaxf(sf[2][e], sf[3][e]));
#pragma unroll
      for (int o = 1; o < 16; o <<= 1) v = fmaxf(v, __shfl_xor(v, o));
      tm[e] = v;
    }
    bool grow = (tm[0] > m_[0] + 8.f) | (tm[1] > m_[1] + 8.f) |
                (tm[2] > m_[2] + 8.f) | (tm[3] > m_[3] + 8.f);
    if (__any(grow)) {
#pragma unroll
      for (int e = 0; e < 4; e++) {
        float mn = fmaxf(m_[e], tm[e]);
        float alpha = __expf(m_[e] - mn);
        m_[e] = mn;
        float rs = 0.f;
#pragma unroll
        for (int ft = 0; ft < 4; ft++) {
          float pv = __expf(sf[ft][e] - mn);
          rs += pv;
          ptw[(quad * 4 + e) * VPAD + ft * 16 + r15] = f2bs(pv);
        }
        l_[e] = l_[e] * alpha + rs;
#pragma unroll
        for (int nt = 0; nt < 8; nt++) of[nt][e] *= alpha;
      }
    } else {
#pragma unroll
      for (int e = 0; e < 4; e++) {
        float rs = 0.f;
#pragma unroll
        for (int ft = 0; ft < 4; ft++) {
          float pv = __expf(sf[ft][e] - m_[e]);
          rs += pv;
          ptw[(quad * 4 + e) * VPAD + ft * 16 + r15] = f2bs(pv);
        }
        l_[e] += rs;
      }
    }
    // ---- PV ----
#pragma unroll
    for (int kc = 0; kc < 2; kc++) {
      bf16x8 pa = *(const bf16x8*)&ptw[r15 * VPAD + kc * 32 + quad * 8];
#pragma unroll
      for (int nt = 0; nt < 8; nt++) {
        bf16x8 vb = *(const bf16x8*)&vtc[(nt * 16 + r15) * VPAD + kc * 32 + quad * 8];
        of[nt] = __builtin_amdgcn_mfma_f32_16x16x32_bf16(pa, vb, of[nt], 0, 0, 0);
      }
    }

    if (nxt >= NKEY) break;
    __syncthreads();       // all waves done reading buf cur; buf cur^1 fully stored
    cur ^= 1; j0 = nxt;
  }

  // ---- final l reduction + normalize + store ----
#pragma unroll
  for (int e = 0; e < 4; e++) {
#pragma unroll
    for (int o = 1; o < 16; o <<= 1) l_[e] += __shfl_xor(l_[e], o);
  }
#pragma unroll
  for (int e = 0; e < 4; e++) {
    int qw = qt * 192 + wid * 16 + quad * 4 + e;
    if (qw >= 360) continue;
    float inv = 1.0f / l_[e];
    int t = qw / 45, pos = qw % 45, wi = pos / 9, wj = pos % 9;
    int tok = ((b * 8 + t) * 20 + nh * 5 + wi) * 36 + nw * 9 + wj;
    bf16* op = ao + (size_t)tok * 512 + n * 128 + r15;
#pragma unroll
    for (int nt = 0; nt < 8; nt++)
      stw(op + nt * 16, of[nt][e] * inv);
  }
}

// ---------- T2T fold + normalize (4 x-positions per thread, float4 store) ----------
__global__ void k_fold(const bf16* __restrict__ h1, float* __restrict__ hf) {
  int idx = blockIdx.x * 256 + threadIdx.x;
  if (idx >= 16 * 40 * 60 * 27) return;
  int x0 = (idx % 27) * 4;
  int tmp = idx / 27;
  int y = tmp % 60; tmp /= 60;
  int c = tmp % 40;
  int bt = tmp / 40;
  float sum[4] = {0.f, 0.f, 0.f, 0.f};
  int cnt[4] = {0, 0, 0, 0};
  for (int ki = y % 3; ki < 7; ki += 3) {
    int num = y + 3 - ki;
    if (num < 0) continue;
    int oh = num / 3;
    if (oh >= 20) continue;
    const bf16* rowb = h1 + (size_t)(bt * 720 + oh * 36) * FFN_ + c * 49 + ki * 7;
#pragma unroll
    for (int xi = 0; xi < 4; xi++) {
      int x = x0 + xi;
      for (int kj = x % 3; kj < 7; kj += 3) {
        int num2 = x + 3 - kj;
        if (num2 < 0) continue;
        int ow = num2 / 3;
        if (ow >= 36) continue;
        sum[xi] += __bfloat162float(rowb[(size_t)ow * FFN_ + kj]);
        cnt[xi]++;
      }
    }
  }
  float4 o;
  o.x = sum[0] / (float)cnt[0];
  o.y = sum[1] / (float)cnt[1];
  o.z = sum[2] / (float)cnt[2];
  o.w = sum[3] / (float)cnt[3];
  *(float4*)&hf[((size_t)(bt * 40 + c) * 60 + y) * 108 + x0] = o;
}

// ---------- T2T unfold + GELU (8 f per thread, 16B store) ----------
__global__ void k_unfold_gelu(const float* __restrict__ hf, bf16* __restrict__ h2) {
  int idx = blockIdx.x * 256 + threadIdx.x;
  if (idx >= NTOK * (FFN_ / 8)) return;
  int token = idx / (FFN_ / 8);
  int f0 = (idx % (FFN_ / 8)) * 8;
  int bt = token / 720, vec = token % 720;
  int oh = vec / 36, ow = vec % 36;
  int c = f0 / 49, k = f0 % 49;
  float g[8];
#pragma unroll
  for (int i = 0; i < 8; i++) {
    int ki = k / 7, kj = k % 7;
    int y = oh * 3 + ki - 3, xx = ow * 3 + kj - 3;
    float v = 0.f;
    if (y >= 0 && y < 60 && xx >= 0 && xx < 108)
      v = hf[((size_t)(bt * 40 + c) * 60 + y) * 108 + xx];
    g[i] = 0.5f * v * (1.0f + erff(v * 0.70710678118654752f));
    k++; if (k == 49) { k = 0; c++; }
  }
  uint4 o;
  o.x = pk2f(g[0], g[1]);
  o.y = pk2f(g[2], g[3]);
  o.z = pk2f(g[4], g[5]);
  o.w = pk2f(g[6], g[7]);
  *(uint4*)&h2[(size_t)token * FFN_ + f0] = o;
}

// ---------- launcher ----------
extern "C" void kernel_launch(void* const* d_in, const int* in_sizes, int n_in,
                              void* d_out, int out_size, void* d_ws, size_t ws_size,
                              hipStream_t stream) {
  (void)in_sizes; (void)n_in; (void)out_size; (void)ws_size;
  const void* x     = d_in[0];
  const void* g1    = d_in[1];
  const void* be1   = d_in[2];
  const void* wqkv  = d_in[3];
  const void* bqkv  = d_in[4];
  const void* wproj = d_in[5];
  const void* bproj = d_in[6];
  const void* wpool = d_in[7];
  const void* bpool = d_in[8];
  const void* g2    = d_in[9];
  const void* be2   = d_in[10];
  const void* w1    = d_in[11];
  const void* bf1   = d_in[12];
  const void* w2    = d_in[13];
  const void* bf2   = d_in[14];

  char* ws = (char*)d_ws;
  size_t off = 0;
  auto alloc = [&](size_t bytes) -> void* {
    void* p = ws + off;
    off += (bytes + 255) & ~(size_t)255;
    return p;
  };

  int*   dflag  = (int*)  alloc(256);
  int*   vtab   = (int*)  alloc(NRK * sizeof(int));
  int*   ksrc   = (int*)  alloc((size_t)32 * NKEY * sizeof(int));
  bf16*  buf2   = (bf16*) alloc((size_t)NTOK * FFN_ * 2);   // qkv+qkvp_b -> h1/h2
  float* pooled = (float*)alloc((size_t)256 * C_ * 4);
  float* x2     = (float*)alloc((size_t)NTOK * C_ * 4);
  float* hf     = (float*)alloc((size_t)16 * 40 * 60 * 108 * 4);
  bf16*  wqkv_t = (bf16*) alloc((size_t)1536 * 512 * 2);
  bf16*  wproj_t= (bf16*) alloc((size_t)512 * 512 * 2);
  bf16*  w1_t   = (bf16*) alloc((size_t)2048 * 512 * 2);    // zero-padded 1960->2048
  bf16*  w2_t   = (bf16*) alloc((size_t)512 * FFN_ * 2);
  float* bqkv_f = (float*)alloc(1536 * 4);
  float* bproj_f= (float*)alloc(512 * 4);
  float* bf1_f  = (float*)alloc(FFN_ * 4);
  float* bf2_f  = (float*)alloc(512 * 4);

  bf16* buf1 = (bf16*)d_out;   // xn -> ao -> y scratch (dead before final GEMM)
  bf16* xn = buf1;
  bf16* ao = buf1;
  bf16* y  = buf1;
  bf16* qkv = buf2;
  bf16* h1  = buf2;
  bf16* qkvpb = buf2 + (size_t)NTOK * 1536;   // 257 rows: 256 pooled + 1 zero row

  // detect + prep + zero-row in one launch
  k_init<<<7, 256, 0, stream>>>(g1, dflag, vtab, qkvpb + (size_t)256 * 1536);
  k_ksrc<<<(32 * NKEY) / 256, 256, 0, stream>>>(vtab, ksrc);

  // weight transpose+convert (LDS-tiled), all biases in one launch
  k_wcvt<<<dim3(24, 8), 256, 0, stream>>>(dflag, wqkv, wqkv_t, 512, 1536, 1536);
  k_wcvt<<<dim3(8, 8), 256, 0, stream>>>(dflag, wproj, wproj_t, 512, 512, 512);
  k_wcvt<<<dim3(32, 8), 256, 0, stream>>>(dflag, w1, w1_t, 512, FFN_, 2048);
  k_wcvt<<<dim3(8, 31), 256, 0, stream>>>(dflag, w2, w2_t, FFN_, 512, 512);
  k_bcvt4<<<18, 256, 0, stream>>>(dflag, bqkv, bqkv_f, bproj, bproj_f,
                                  bf1, bf1_f, bf2, bf2_f);

  // LN1
  k_ln<<<NTOK, 256, 0, stream>>>(dflag, 0, x, g1, be1, xn);

  // window pooling
  k_pool<<<512, 256, 0, stream>>>(dflag, xn, wpool, bpool, pooled);

  // qkv = xn @ wqkv + bqkv
  k_gemm_m<0><<<dim3(12, 90), 256, 0, stream>>>(
      nullptr, xn, wqkv_t, bqkv_f, nullptr, qkv, NTOK, 1536, 512);

  // qkv_p = pooled @ wqkv + bqkv -> bf16 rows appended after qkv
  k_gemm_small<<<dim3(6, 32), 256, 0, stream>>>(dflag, pooled, wqkv, bqkv, qkvpb);

  // MFMA flash attention: 256 blocks (1/CU), 12 waves, 192 queries per block
  k_attn_m<<<dim3(32, 2, NH_), 768, 0, stream>>>(qkv, ksrc, ao);

  // x2 = x + ao @ wproj + bproj
  k_gemm_m<1><<<dim3(4, 90), 256, 0, stream>>>(
      dflag, ao, wproj_t, bproj_f, x, x2, NTOK, 512, 512);

  // LN2 -> y
  k_ln<<<NTOK, 256, 0, stream>>>(dflag, 1, x2, g2, be2, y);

  // h1 = y @ w1 + bf1
  k_gemm_m<0><<<dim3(16, 90), 256, 0, stream>>>(
      nullptr, y, w1_t, bf1_f, nullptr, h1, NTOK, FFN_, 512);

  // T2T fold + normalize (4x vectorized)
  k_fold<<<(16 * 40 * 60 * 27) / 256 + 1, 256, 0, stream>>>(h1, hf);

  // T2T unfold + GELU (8x vectorized, in place into buf2)
  k_unfold_gelu<<<(NTOK * (FFN_ / 8)) / 256, 256, 0, stream>>>(hf, h1);

  // out = x2 + gelu_h @ w2 + bf2
  k_gemm_m<2><<<dim3(4, 90), 256, 0, stream>>>(
      dflag, h1, w2_t, bf2_f, x2, d_out, NTOK, 512, FFN_);
}

// Round 9
// 542.947 us; speedup vs baseline: 1.2011x; 1.2011x over previous
//
#include <hip/hip_runtime.h>
#include <hip/hip_bf16.h>
#include <math.h>

typedef __hip_bfloat16 bf16;
typedef __attribute__((ext_vector_type(8))) short bf16x8;
typedef __attribute__((ext_vector_type(4))) float f32x4;

#define DEVI __device__ __forceinline__

// ---------- constants ----------
#define C_ 512
#define NH_ 4
#define NTOK 11520          // B*T*H*W
#define NKEY 1680           // 360 local + 960 rolled + 360 pooled
#define NRK 120
#define FFN_ 1960
#define ZROW (NTOK + 256)   // zeroed key row for invalid slots

// ---------- helpers ----------
DEVI float ldf(const bf16* p) { return __bfloat162float(*p); }
DEVI float ldf(const float* p) { return *p; }
DEVI void stw(bf16* p, float v) { *p = __float2bfloat16(v); }
DEVI void stw(float* p, float v) { *p = v; }
DEVI unsigned short f2bs(float f) { bf16 h = __float2bfloat16(f); return *(unsigned short*)&h; }

// dtype-dispatched scalar load: DT=0 bf16, DT=1 f32
template <int DT> DEVI float ldw(const void* p, size_t i) {
  if (DT == 0) return __bfloat162float(((const bf16*)p)[i]);
  else         return ((const float*)p)[i];
}

// async global->LDS, 16B per lane; lptr is wave-uniform base (HW adds lane*16)
DEVI void gload_lds16(const void* g, void* l) {
  __builtin_amdgcn_global_load_lds(
      (const __attribute__((address_space(1))) void*)g,
      (__attribute__((address_space(3))) void*)l, 16, 0, 0);
}

// ---------- K_init: dtype detect + valid-index table + zero-row ----------
__global__ void k_init(const void* __restrict__ g1, int* __restrict__ flag,
                       int* __restrict__ table, bf16* __restrict__ zp) {
  if (blockIdx.x == 0) {
    if (threadIdx.x == 0) {
      const unsigned short* p = (const unsigned short*)g1;
      *flag = (p[0] == 0x3F80u) ? 0 : 1;
      int cnt = 0;
      for (int pq = 0; pq < 4; pq++)
        for (int wi = 0; wi < 5; wi++)
          for (int wj = 0; wj < 9; wj++) {
            bool invalid;
            if (pq == 0)      invalid = (wi < 3) && (wj < 5);
            else if (pq == 1) invalid = (wi < 3) && (wj >= 4);
            else if (pq == 2) invalid = (wi >= 2) && (wj < 5);
            else              invalid = (wi >= 2) && (wj >= 4);
            if (!invalid) table[cnt++] = pq * 45 + wi * 9 + wj;
          }
    }
  } else {
    zp[(blockIdx.x - 1) * 256 + threadIdx.x] = __float2bfloat16(0.f);
  }
}

// ---------- K0b: per-window key-source table ksrc[32][1680] ----------
// values: token row (<NTOK) for local/rolled, NTOK+pidx for pooled, -1 invalid
__global__ void k_ksrc(const int* __restrict__ vtab, int* __restrict__ ksrc) {
  int idx = blockIdx.x * 256 + threadIdx.x;
  if (idx >= 32 * NKEY) return;
  int w = idx / NKEY, j = idx % NKEY;
  int b = w >> 4, nh = (w >> 2) & 3, nw = w & 3;
  int val;
  if (j < 360) {
    int t = j / 45, pos = j % 45, wi = pos / 9, wj2 = pos % 9;
    val = ((b * 8 + t) * 20 + nh * 5 + wi) * 36 + nw * 9 + wj2;
  } else if (j < 1320) {
    int jj = j - 360;
    int t = jj / 120, r = jj % 120;
    int id = vtab[r];
    int p = id / 45, pos = id % 45, wi = pos / 9, wj2 = pos % 9;
    int sh = (p < 2) ? -2 : 2;
    int sw = (p & 1) ? 4 : -4;
    int hh = nh * 5 + wi - sh;
    if (hh < 0) hh += 20; else if (hh >= 20) hh -= 20;
    int ww2 = nw * 9 + wj2 - sw;
    if (ww2 < 0) ww2 += 36; else if (ww2 >= 36) ww2 -= 36;
    val = ((b * 8 + t) * 20 + hh) * 36 + ww2;
  } else {
    int jj = j - 1320;
    int t = jj / 45, kidx = jj % 45, ki = kidx / 9, kj = kidx % 9;
    int snh = nh + ki - 2, snw = nw + kj - 4;
    if (snh < 0 || snh >= 4 || snw < 0 || snw >= 4) val = -1;
    else val = NTOK + (b * 8 + t) * 16 + snh * 4 + snw;
  }
  ksrc[idx] = val;
}

// ---------- weight convert+transpose (LDS-tiled, both sides coalesced) ----------
// out[n][k] = in[k][n], bf16, zero-pad n>=N.  grid: (ceil(Npad/64), ceil(K/64))
template <int DT>
DEVI void wcvt_body(const void* in, bf16* out, int K, int N, int Npad) {
  __shared__ float t[64][65];
  const int n0 = blockIdx.x * 64;
  const int k0 = blockIdx.y * 64;
  const int tx = threadIdx.x & 63, tg = threadIdx.x >> 6;
#pragma unroll
  for (int r = 0; r < 16; r++) {
    int k = k0 + r * 4 + tg;
    int nn = n0 + tx;
    float v = (k < K && nn < N) ? ldw<DT>(in, (size_t)k * N + nn) : 0.f;
    t[r * 4 + tg][tx] = v;
  }
  __syncthreads();
#pragma unroll
  for (int r = 0; r < 16; r++) {
    int nn = n0 + r * 4 + tg;
    int k = k0 + tx;
    if (nn < Npad && k < K)
      out[(size_t)nn * K + k] = __float2bfloat16(t[tx][r * 4 + tg]);
  }
}
__global__ void k_wcvt(const int* __restrict__ dflag, const void* __restrict__ in,
                       bf16* __restrict__ out, int K, int N, int Npad) {
  if (*dflag == 0) wcvt_body<0>(in, out, K, N, Npad);
  else             wcvt_body<1>(in, out, K, N, Npad);
}

// ---------- bias convert -> f32 (all four biases in one launch) ----------
// grid 18 blocks: [0,6)=bqkv(1536) [6,8)=bproj(512) [8,16)=bf1(1960 pad) [16,18)=bf2(512)
__global__ void k_bcvt4(const int* __restrict__ dflag,
                        const void* __restrict__ b0, float* __restrict__ o0,
                        const void* __restrict__ b1, float* __restrict__ o1,
                        const void* __restrict__ b2, float* __restrict__ o2,
                        const void* __restrict__ b3, float* __restrict__ o3) {
  int dt = *dflag;
  int bx = blockIdx.x;
  const void* src; float* dst; int n, i;
  if (bx < 6)       { src = b0; dst = o0; n = 1536; i = bx * 256 + threadIdx.x; }
  else if (bx < 8)  { src = b1; dst = o1; n = 512;  i = (bx - 6) * 256 + threadIdx.x; }
  else if (bx < 16) { src = b2; dst = o2; n = FFN_; i = (bx - 8) * 256 + threadIdx.x; }
  else              { src = b3; dst = o3; n = 512;  i = (bx - 16) * 256 + threadIdx.x; }
  if (i < n) dst[i] = (dt == 0) ? ldw<0>(src, i) : ldw<1>(src, i);
}

// ---------- LayerNorm over C=512 ----------
template <int DTIN, int DTP>
DEVI void ln_body(const void* xin, const void* g, const void* be, bf16* out) {
  const int tok = blockIdx.x;
  const int tid = threadIdx.x;
  const size_t base = (size_t)tok * C_;
  float v0 = ldw<DTIN>(xin, base + tid);
  float v1 = ldw<DTIN>(xin, base + tid + 256);
  float s = v0 + v1, ss = v0 * v0 + v1 * v1;
#pragma unroll
  for (int o = 32; o; o >>= 1) { s += __shfl_xor(s, o); ss += __shfl_xor(ss, o); }
  __shared__ float sh[10];
  const int lane = tid & 63, wv = tid >> 6;
  if (lane == 0) { sh[wv] = s; sh[4 + wv] = ss; }
  __syncthreads();
  if (tid == 0) {
    float a = sh[0] + sh[1] + sh[2] + sh[3];
    float q = sh[4] + sh[5] + sh[6] + sh[7];
    float mu = a * (1.0f / C_);
    float var = q * (1.0f / C_) - mu * mu;
    sh[8] = mu; sh[9] = rsqrtf(fmaxf(var, 0.f) + 1e-5f);
  }
  __syncthreads();
  float mu = sh[8], inv = sh[9];
  stw(out + base + tid,
      (v0 - mu) * inv * ldw<DTP>(g, tid) + ldw<DTP>(be, tid));
  stw(out + base + tid + 256,
      (v1 - mu) * inv * ldw<DTP>(g, tid + 256) + ldw<DTP>(be, tid + 256));
}
// mode 0: input dtype follows dflag (LN1); mode 1: input always f32 (LN2)
__global__ void k_ln(const int* __restrict__ dflag, int mode,
                     const void* __restrict__ xin, const void* __restrict__ g,
                     const void* __restrict__ be, bf16* __restrict__ out) {
  int dt = *dflag;
  if (mode == 0) {
    if (dt == 0) ln_body<0, 0>(xin, g, be, out);
    else         ln_body<1, 1>(xin, g, be, out);
  } else {
    if (dt == 0) ln_body<1, 0>(xin, g, be, out);
    else         ln_body<1, 1>(xin, g, be, out);
  }
}

// ---------- window pooling ----------
template <int DT>
DEVI void pool_body(const bf16* xn, const void* wpool, const void* bpool,
                    float* pooled) {
  int idx = blockIdx.x * blockDim.x + threadIdx.x;
  if (idx >= 256 * C_) return;
  int c = idx & (C_ - 1);
  int fw = idx >> 9;
  int nw = fw & 3, nh = (fw >> 2) & 3;
  int bt = fw >> 4;
  float acc = ldw<DT>(bpool, 0);
  for (int wi = 0; wi < 5; wi++) {
    int hh = nh * 5 + wi;
    const bf16* base = xn + (((size_t)(bt * 20 + hh)) * 36 + nw * 9) * C_ + c;
    for (int wj = 0; wj < 9; wj++)
      acc += __bfloat162float(base[(size_t)wj * C_]) * ldw<DT>(wpool, wi * 9 + wj);
  }
  pooled[idx] = acc;
}
__global__ void k_pool(const int* __restrict__ dflag, const bf16* __restrict__ xn,
                       const void* __restrict__ wpool, const void* __restrict__ bpool,
                       float* __restrict__ pooled) {
  if (*dflag == 0) pool_body<0>(xn, wpool, bpool, pooled);
  else             pool_body<1>(xn, wpool, bpool, pooled);
}

// ---------- small GEMM pooled(f32) @ wqkv + bqkv -> qkvp_b (bf16, stride 1536) ----------
// grid (6, 32): n0 = bx*256, m0 = by*8; A tile in LDS, B reads coalesced.
template <int DT>
DEVI void gemm_small_body(const float* A, const void* Bw, const void* bias,
                          bf16* Cc) {
  __shared__ float As[8][512];
  const int n = blockIdx.x * 256 + threadIdx.x;
  const int m0 = blockIdx.y * 8;
  for (int i = threadIdx.x; i < 8 * 512; i += 256)
    As[i >> 9][i & 511] = A[(size_t)(m0 + (i >> 9)) * 512 + (i & 511)];
  __syncthreads();
  float acc[8];
  float bv = ldw<DT>(bias, n);
#pragma unroll
  for (int mm = 0; mm < 8; mm++) acc[mm] = bv;
  for (int k = 0; k < 512; k++) {
    float b = ldw<DT>(Bw, (size_t)k * 1536 + n);
#pragma unroll
    for (int mm = 0; mm < 8; mm++) acc[mm] += As[mm][k] * b;
  }
#pragma unroll
  for (int mm = 0; mm < 8; mm++)
    Cc[(size_t)(m0 + mm) * 1536 + n] = __float2bfloat16(acc[mm]);
}
__global__ void k_gemm_small(const int* __restrict__ dflag, const float* __restrict__ A,
                             const void* __restrict__ Bw, const void* __restrict__ bias,
                             bf16* __restrict__ Cc) {
  if (*dflag == 0) gemm_small_body<0>(A, Bw, bias, Cc);
  else             gemm_small_body<1>(A, Bw, bias, Cc);
}

// ---------- MFMA GEMM: out[M][N] = A[M][K](bf16) @ Bt[N][K]^T(bf16) + bias(f32) ----------
// BK=64 as two [128][32] chunks (keeps proven 64B-row LDS layout / bank behavior)
// -> one barrier pair per 64-k step (R7: -21us vs BK=32).
// XCD-bijective block swizzle (T1/m204): all grids have nwg%8==0; chunked remap
// keeps blocks sharing an A-panel on the same XCD -> panel L2-resident.
// RES=0: out bf16.  RES=1: out f32, resid dtype = *dflag.  RES=2: resid f32, out dtype = *dflag.
template <int RES>
__global__ __launch_bounds__(256) void k_gemm_m(const int* __restrict__ dflag,
                                                const bf16* __restrict__ A,
                                                const bf16* __restrict__ Bt,
                                                const float* __restrict__ bias,
                                                const void* __restrict__ resid,
                                                void* __restrict__ out,
                                                int M, int N, int K) {
  const int dt = dflag ? *dflag : 0;
  __shared__ __align__(16) unsigned short As[2][128 * 32];
  __shared__ __align__(16) unsigned short Bs[2][128 * 32];
  const int tid = threadIdx.x;
  const int lane = tid & 63, wid = tid >> 6;
  const int r15 = lane & 15, quad = lane >> 4;
  const int wm = wid >> 1, wn = wid & 1;
  // XCD-aware chunked swizzle (requires nwg % 8 == 0; all call sites satisfy)
  const int nbx = gridDim.x;
  const int lin = blockIdx.x + nbx * blockIdx.y;
  const int cpx = (nbx * gridDim.y) >> 3;
  const int swz = (lin & 7) * cpx + (lin >> 3);
  const int m0 = (swz / nbx) * 128, n0 = (swz % nbx) * 128;

  f32x4 acc[4][4];
#pragma unroll
  for (int i = 0; i < 4; i++)
#pragma unroll
    for (int j = 0; j < 4; j++)
#pragma unroll
      for (int e = 0; e < 4; e++) acc[i][j][e] = 0.f;

  const int lrow = lane >> 2, lcol = (lane & 3) * 8;

  for (int k0 = 0; k0 < K; k0 += 64) {
    int rem = K - k0;
    if (rem >= 64) {
      const bf16* ga = A + (size_t)(m0 + wid * 32 + lrow) * K + k0 + lcol;
      gload_lds16(ga, &As[0][wid * 1024]);
      gload_lds16(ga + (size_t)16 * K, &As[0][wid * 1024 + 512]);
      gload_lds16(ga + 32, &As[1][wid * 1024]);
      gload_lds16(ga + (size_t)16 * K + 32, &As[1][wid * 1024 + 512]);
      const bf16* gb = Bt + (size_t)(n0 + wid * 32 + lrow) * K + k0 + lcol;
      gload_lds16(gb, &Bs[0][wid * 1024]);
      gload_lds16(gb + (size_t)16 * K, &Bs[0][wid * 1024 + 512]);
      gload_lds16(gb + 32, &Bs[1][wid * 1024]);
      gload_lds16(gb + (size_t)16 * K + 32, &Bs[1][wid * 1024 + 512]);
    } else {
      // tail (rem multiple of 8, < 64): 32 rows x 64 cols per pass, 4 passes
      int r = tid >> 3, c = (tid & 7) * 8;
      uint4 z = make_uint4(0, 0, 0, 0);
      int h = c >> 5, cc = c & 31;
#pragma unroll
      for (int p = 0; p < 4; p++) {
        int row = r + p * 32;
        uint4 av = z, bv = z;
        if (c < rem) {
          av = *(const uint4*)(A + (size_t)(m0 + row) * K + k0 + c);
          bv = *(const uint4*)(Bt + (size_t)(n0 + row) * K + k0 + c);
        }
        *(uint4*)&As[h][row * 32 + cc] = av;
        *(uint4*)&Bs[h][row * 32 + cc] = bv;
      }
    }
    __syncthreads();

#pragma unroll
    for (int h = 0; h < 2; h++) {
      bf16x8 af[4], bfr[4];
#pragma unroll
      for (int mf = 0; mf < 4; mf++)
        af[mf] = *(const bf16x8*)&As[h][(wm * 64 + mf * 16 + r15) * 32 + quad * 8];
#pragma unroll
      for (int nf = 0; nf < 4; nf++)
        bfr[nf] = *(const bf16x8*)&Bs[h][(wn * 64 + nf * 16 + r15) * 32 + quad * 8];
#pragma unroll
      for (int mf = 0; mf < 4; mf++)
#pragma unroll
        for (int nf = 0; nf < 4; nf++)
          acc[mf][nf] = __builtin_amdgcn_mfma_f32_16x16x32_bf16(af[mf], bfr[nf],
                                                                acc[mf][nf], 0, 0, 0);
    }
    __syncthreads();
  }

#pragma unroll
  for (int nf = 0; nf < 4; nf++) {
    int n = n0 + wn * 64 + nf * 16 + r15;
    if (n >= N) continue;
    float bv = bias[n];
#pragma unroll
    for (int mf = 0; mf < 4; mf++) {
      int mb = m0 + wm * 64 + mf * 16 + quad * 4;
#pragma unroll
      for (int e = 0; e < 4; e++) {
        size_t off = (size_t)(mb + e) * N + n;
        float v = acc[mf][nf][e] + bv;
        if (RES == 1) v += (dt == 0) ? ldw<0>(resid, off) : ldw<1>(resid, off);
        else if (RES == 2) v += ((const float*)resid)[off];
        if (RES == 0) ((bf16*)out)[off] = __float2bfloat16(v);
        else if (RES == 1) ((float*)out)[off] = v;
        else {
          if (dt == 0) ((bf16*)out)[off] = __float2bfloat16(v);
          else         ((float*)out)[off] = v;
        }
      }
    }
  }
}

// ---------- MFMA flash attention (768 thr, 12 waves, K/V double-buffered) ----------
// grid: (32 windows, 2 qtiles, 4 heads) = 256 blocks (1 per CU)
// All key sources (local/rolled/pooled/invalid) are bf16 rows of stride 1536 in
// one array (pooled rows appended at NTOK, zero row at ZROW) -> branch-free staging.
// Staging registers are NAMED SCALARS (k0..k3 / v0,v1), not arrays: prevents the
// promote-alloca pass from spilling them to LDS (R2/R3 regression: LDS_Block_Size
// 107008->156160). Online softmax uses defer-max (THR=8, HK-style): skip the
// O-rescale + max update when no query row grew by >8 (R2 vs R3 evidence: -8us).
#define KT 64
#define KPAD 136
#define VPAD 72
__global__ __launch_bounds__(768) void k_attn_m(const bf16* __restrict__ qkv,
                                                const int* __restrict__ ksrc,
                                                bf16* __restrict__ ao) {
  __shared__ int ks_l[NKEY];
  __shared__ __align__(16) unsigned short ktl[2][KT * KPAD];    // K [key][dim]
  __shared__ __align__(16) unsigned short vtl[2][128 * VPAD];   // V^T [dim][key]
  __shared__ __align__(16) unsigned short ptl[12 * 16 * VPAD];  // P per wave [q][key]
  __shared__ float maskv[2][KT];

  const int tid = threadIdx.x;
  const int lane = tid & 63, wid = tid >> 6;   // wid 0..11
  const int r15 = lane & 15, quad = lane >> 4;
  const int w = blockIdx.x, qt = blockIdx.y, n = blockIdx.z;
  const int b = w >> 4, nh = (w >> 2) & 3, nw = w & 3;
  const unsigned short* qkvs = (const unsigned short*)qkv;

  for (int j = tid; j < NKEY; j += 768) ks_l[j] = ksrc[w * NKEY + j];

  // Q A-fragments (16 queries per wave), clamped for padding
  bf16x8 qf[4];
  {
    int qw = qt * 192 + wid * 16 + r15;
    int qc2 = qw < 360 ? qw : 359;
    int t = qc2 / 45, pos = qc2 % 45, wi = pos / 9, wj = pos % 9;
    int tok = ((b * 8 + t) * 20 + nh * 5 + wi) * 36 + nw * 9 + wj;
    const unsigned short* qp = qkvs + (size_t)tok * 1536 + n * 128 + quad * 8;
#pragma unroll
    for (int c = 0; c < 4; c++)
      qf[c] = *(const bf16x8*)(qp + c * 32);
  }

  f32x4 of[8];
#pragma unroll
  for (int nt = 0; nt < 8; nt++)
#pragma unroll
    for (int e = 0; e < 4; e++) of[nt][e] = 0.f;
  float m_[4], l_[4];   // l_ is a PER-LANE partial sum (reduced once at the end)
#pragma unroll
  for (int e = 0; e < 4; e++) { m_[e] = -1e30f; l_[e] = 0.f; }

  unsigned short* ptw = &ptl[wid * 16 * VPAD];

  // staging roles
  const bool isK = (wid < 4);
  const int kr = tid >> 2, kp = tid & 3;   // K role (tid < 256)
  const int vr = lane, vp8 = wid - 4;      // V role (wid >= 4)
  // named staging registers (NOT arrays -> guaranteed VGPRs)
  uint4 k0, k1, k2, k3, v0, v1;
  float mreg = -30000.f;
  // wave-invariant base offsets
  const unsigned short* kbase = qkvs + 512 + n * 128 + kp * 32;
  const unsigned short* vbase = qkvs + 1024 + n * 128 + vp8 * 16;

  auto load_tile = [&](int j0) {
    int cnt = NKEY - j0; if (cnt > KT) cnt = KT;
    if (isK) {
      int s0 = (kr < cnt) ? ks_l[j0 + kr] : -1;
      mreg = (s0 < 0) ? -30000.f : 0.f;
      int row = (s0 < 0) ? ZROW : s0;
      const uint4* kq = (const uint4*)(kbase + (size_t)row * 1536);
      k0 = kq[0]; k1 = kq[1]; k2 = kq[2]; k3 = kq[3];
    } else {
      int s1 = (vr < cnt) ? ks_l[j0 + vr] : -1;
      int row = (s1 < 0) ? ZROW : s1;
      const uint4* vq = (const uint4*)(vbase + (size_t)row * 1536);
      v0 = vq[0]; v1 = vq[1];
    }
  };

  auto store_tile = [&](int buf) {
    if (isK) {
      if (kp == 0) maskv[buf][kr] = mreg;
      unsigned short* kb = &ktl[buf][kr * KPAD + kp * 32];
      *(uint4*)&kb[0]  = k0;
      *(uint4*)&kb[8]  = k1;
      *(uint4*)&kb[16] = k2;
      *(uint4*)&kb[24] = k3;
    } else {
      unsigned short* vb = &vtl[buf][0];
      int d0 = vp8 * 16;
      vb[(d0 + 0) * VPAD + vr]  = (unsigned short)(v0.x & 0xFFFFu);
      vb[(d0 + 1) * VPAD + vr]  = (unsigned short)(v0.x >> 16);
      vb[(d0 + 2) * VPAD + vr]  = (unsigned short)(v0.y & 0xFFFFu);
      vb[(d0 + 3) * VPAD + vr]  = (unsigned short)(v0.y >> 16);
      vb[(d0 + 4) * VPAD + vr]  = (unsigned short)(v0.z & 0xFFFFu);
      vb[(d0 + 5) * VPAD + vr]  = (unsigned short)(v0.z >> 16);
      vb[(d0 + 6) * VPAD + vr]  = (unsigned short)(v0.w & 0xFFFFu);
      vb[(d0 + 7) * VPAD + vr]  = (unsigned short)(v0.w >> 16);
      vb[(d0 + 8) * VPAD + vr]  = (unsigned short)(v1.x & 0xFFFFu);
      vb[(d0 + 9) * VPAD + vr]  = (unsigned short)(v1.x >> 16);
      vb[(d0 + 10) * VPAD + vr] = (unsigned short)(v1.y & 0xFFFFu);
      vb[(d0 + 11) * VPAD + vr] = (unsigned short)(v1.y >> 16);
      vb[(d0 + 12) * VPAD + vr] = (unsigned short)(v1.z & 0xFFFFu);
      vb[(d0 + 13) * VPAD + vr] = (unsigned short)(v1.z >> 16);
      vb[(d0 + 14) * VPAD + vr] = (unsigned short)(v1.w & 0xFFFFu);
      vb[(d0 + 15) * VPAD + vr] = (unsigned short)(v1.w >> 16);
    }
  };

  __syncthreads();        // ks_l ready
  load_tile(0);
  store_tile(0);
  load_tile(KT);          // prefetch tile 1 into regs (NKEY > KT always)
  __syncthreads();        // buf 0 ready

  int cur = 0, j0 = 0;
  while (true) {
    int nxt = j0 + KT;
    if (nxt < NKEY) {
      store_tile(cur ^ 1);                        // regs (tile nxt) -> idle buffer
      if (nxt + KT < NKEY) load_tile(nxt + KT);   // prefetch tile nxt+KT
    }

    const unsigned short* ktc = &ktl[cur][0];
    const unsigned short* vtc = &vtl[cur][0];
    const float* mkc = maskv[cur];

    // ---- QK^T ----
    f32x4 sf[4];
#pragma unroll
    for (int ft = 0; ft < 4; ft++)
#pragma unroll
      for (int e = 0; e < 4; e++) sf[ft][e] = 0.f;
#pragma unroll
    for (int kc = 0; kc < 4; kc++) {
      bf16x8 a = qf[kc];
#pragma unroll
      for (int ft = 0; ft < 4; ft++) {
        bf16x8 bb = *(const bf16x8*)&ktc[(ft * 16 + r15) * KPAD + kc * 32 + quad * 8];
        sf[ft] = __builtin_amdgcn_mfma_f32_16x16x32_bf16(a, bb, sf[ft], 0, 0, 0);
      }
    }
    const float scl = 0.088388347648318447f;
#pragma unroll
    for (int ft = 0; ft < 4; ft++) {
      float mk = mkc[ft * 16 + r15];
#pragma unroll
      for (int e = 0; e < 4; e++) sf[ft][e] = sf[ft][e] * scl + mk;
    }
    // ---- online softmax (defer-max THR=8; lazy per-lane l partial) ----
    float tm[4];
#pragma unroll
    for (int e = 0; e < 4; e++) {
      float v = fmaxf(fmaxf(sf[0][e], sf[1][e]), fmaxf(sf[2][e], sf[3][e]));
#pragma unroll
      for (int o = 1; o < 16; o <<= 1) v = fmaxf(v, __shfl_xor(v, o));
      tm[e] = v;
    }
    bool grow = (tm[0] > m_[0] + 8.f) | (tm[1] > m_[1] + 8.f) |
                (tm[2] > m_[2] + 8.f) | (tm[3] > m_[3] + 8.f);
    if (__any(grow)) {
#pragma unroll
      for (int e = 0; e < 4; e++) {
        float mn = fmaxf(m_[e], tm[e]);
        float alpha = __expf(m_[e] - mn);
        m_[e] = mn;
        float rs = 0.f;
#pragma unroll
        for (int ft = 0; ft < 4; ft++) {
          float pv = __expf(sf[ft][e] - mn);
          rs += pv;
          ptw[(quad * 4 + e) * VPAD + ft * 16 + r15] = f2bs(pv);
        }
        l_[e] = l_[e] * alpha + rs;
#pragma unroll
        for (int nt = 0; nt < 8; nt++) of[nt][e] *= alpha;
      }
    } else {
#pragma unroll
      for (int e = 0; e < 4; e++) {
        float rs = 0.f;
#pragma unroll
        for (int ft = 0; ft < 4; ft++) {
          float pv = __expf(sf[ft][e] - m_[e]);
          rs += pv;
          ptw[(quad * 4 + e) * VPAD + ft * 16 + r15] = f2bs(pv);
        }
        l_[e] += rs;
      }
    }
    // ---- PV ----
#pragma unroll
    for (int kc = 0; kc < 2; kc++) {
      bf16x8 pa = *(const bf16x8*)&ptw[r15 * VPAD + kc * 32 + quad * 8];
#pragma unroll
      for (int nt = 0; nt < 8; nt++) {
        bf16x8 vb = *(const bf16x8*)&vtc[(nt * 16 + r15) * VPAD + kc * 32 + quad * 8];
        of[nt] = __builtin_amdgcn_mfma_f32_16x16x32_bf16(pa, vb, of[nt], 0, 0, 0);
      }
    }

    if (nxt >= NKEY) break;
    __syncthreads();       // all waves done reading buf cur; buf cur^1 fully stored
    cur ^= 1; j0 = nxt;
  }

  // ---- final l reduction + normalize + store ----
#pragma unroll
  for (int e = 0; e < 4; e++) {
#pragma unroll
    for (int o = 1; o < 16; o <<= 1) l_[e] += __shfl_xor(l_[e], o);
  }
#pragma unroll
  for (int e = 0; e < 4; e++) {
    int qw = qt * 192 + wid * 16 + quad * 4 + e;
    if (qw >= 360) continue;
    float inv = 1.0f / l_[e];
    int t = qw / 45, pos = qw % 45, wi = pos / 9, wj = pos % 9;
    int tok = ((b * 8 + t) * 20 + nh * 5 + wi) * 36 + nw * 9 + wj;
    bf16* op = ao + (size_t)tok * 512 + n * 128 + r15;
#pragma unroll
    for (int nt = 0; nt < 8; nt++)
      stw(op + nt * 16, of[nt][e] * inv);
  }
}

// ---------- T2T fold + normalize (scalar, coalesced reads — R7 version) ----------
__global__ void k_fold(const bf16* __restrict__ h1, float* __restrict__ hf) {
  int idx = blockIdx.x * 256 + threadIdx.x;
  if (idx >= 16 * 40 * 60 * 108) return;
  int x = idx % 108;
  int tmp = idx / 108;
  int y = tmp % 60; tmp /= 60;
  int c = tmp % 40;
  int bt = tmp / 40;
  float sum = 0.f;
  int cnt = 0;
  for (int ki = y % 3; ki < 7; ki += 3) {
    int num = y + 3 - ki;
    if (num < 0) continue;
    int oh = num / 3;
    if (oh >= 20) continue;
    for (int kj = x % 3; kj < 7; kj += 3) {
      int num2 = x + 3 - kj;
      if (num2 < 0) continue;
      int ow = num2 / 3;
      if (ow >= 36) continue;
      sum += __bfloat162float(
          h1[(size_t)(bt * 720 + oh * 36 + ow) * FFN_ + c * 49 + ki * 7 + kj]);
      cnt++;
    }
  }
  hf[idx] = sum / (float)cnt;
}

// ---------- T2T unfold + GELU (scalar, coalesced reads — R7 version) ----------
__global__ void k_unfold_gelu(const float* __restrict__ hf, bf16* __restrict__ h2) {
  int idx = blockIdx.x * 256 + threadIdx.x;
  if (idx >= NTOK * FFN_) return;
  int f = idx % FFN_;
  int token = idx / FFN_;
  int c = f / 49, k = f % 49, ki = k / 7, kj = k % 7;
  int bt = token / 720, vec = token % 720;
  int oh = vec / 36, ow = vec % 36;
  int y = oh * 3 + ki - 3, x = ow * 3 + kj - 3;
  float v = 0.f;
  if (y >= 0 && y < 60 && x >= 0 && x < 108)
    v = hf[((size_t)(bt * 40 + c) * 60 + y) * 108 + x];
  float g = 0.5f * v * (1.0f + erff(v * 0.70710678118654752f));
  stw(h2 + idx, g);
}

// ---------- launcher ----------
extern "C" void kernel_launch(void* const* d_in, const int* in_sizes, int n_in,
                              void* d_out, int out_size, void* d_ws, size_t ws_size,
                              hipStream_t stream) {
  (void)in_sizes; (void)n_in; (void)out_size; (void)ws_size;
  const void* x     = d_in[0];
  const void* g1    = d_in[1];
  const void* be1   = d_in[2];
  const void* wqkv  = d_in[3];
  const void* bqkv  = d_in[4];
  const void* wproj = d_in[5];
  const void* bproj = d_in[6];
  const void* wpool = d_in[7];
  const void* bpool = d_in[8];
  const void* g2    = d_in[9];
  const void* be2   = d_in[10];
  const void* w1    = d_in[11];
  const void* bf1   = d_in[12];
  const void* w2    = d_in[13];
  const void* bf2   = d_in[14];

  char* ws = (char*)d_ws;
  size_t off = 0;
  auto alloc = [&](size_t bytes) -> void* {
    void* p = ws + off;
    off += (bytes + 255) & ~(size_t)255;
    return p;
  };

  int*   dflag  = (int*)  alloc(256);
  int*   vtab   = (int*)  alloc(NRK * sizeof(int));
  int*   ksrc   = (int*)  alloc((size_t)32 * NKEY * sizeof(int));
  bf16*  buf2   = (bf16*) alloc((size_t)NTOK * FFN_ * 2);   // qkv+qkvp_b -> h1/h2
  float* pooled = (float*)alloc((size_t)256 * C_ * 4);
  float* x2     = (float*)alloc((size_t)NTOK * C_ * 4);
  float* hf     = (float*)alloc((size_t)16 * 40 * 60 * 108 * 4);
  bf16*  wqkv_t = (bf16*) alloc((size_t)1536 * 512 * 2);
  bf16*  wproj_t= (bf16*) alloc((size_t)512 * 512 * 2);
  bf16*  w1_t   = (bf16*) alloc((size_t)2048 * 512 * 2);    // zero-padded 1960->2048
  bf16*  w2_t   = (bf16*) alloc((size_t)512 * FFN_ * 2);
  float* bqkv_f = (float*)alloc(1536 * 4);
  float* bproj_f= (float*)alloc(512 * 4);
  float* bf1_f  = (float*)alloc(FFN_ * 4);
  float* bf2_f  = (float*)alloc(512 * 4);

  bf16* buf1 = (bf16*)d_out;   // xn -> ao -> y scratch (dead before final GEMM)
  bf16* xn = buf1;
  bf16* ao = buf1;
  bf16* y  = buf1;
  bf16* qkv = buf2;
  bf16* h1  = buf2;
  bf16* qkvpb = buf2 + (size_t)NTOK * 1536;   // 257 rows: 256 pooled + 1 zero row

  // detect + prep + zero-row in one launch
  k_init<<<7, 256, 0, stream>>>(g1, dflag, vtab, qkvpb + (size_t)256 * 1536);
  k_ksrc<<<(32 * NKEY) / 256, 256, 0, stream>>>(vtab, ksrc);

  // weight transpose+convert (LDS-tiled), all biases in one launch
  k_wcvt<<<dim3(24, 8), 256, 0, stream>>>(dflag, wqkv, wqkv_t, 512, 1536, 1536);
  k_wcvt<<<dim3(8, 8), 256, 0, stream>>>(dflag, wproj, wproj_t, 512, 512, 512);
  k_wcvt<<<dim3(32, 8), 256, 0, stream>>>(dflag, w1, w1_t, 512, FFN_, 2048);
  k_wcvt<<<dim3(8, 31), 256, 0, stream>>>(dflag, w2, w2_t, FFN_, 512, 512);
  k_bcvt4<<<18, 256, 0, stream>>>(dflag, bqkv, bqkv_f, bproj, bproj_f,
                                  bf1, bf1_f, bf2, bf2_f);

  // LN1
  k_ln<<<NTOK, 256, 0, stream>>>(dflag, 0, x, g1, be1, xn);

  // window pooling
  k_pool<<<512, 256, 0, stream>>>(dflag, xn, wpool, bpool, pooled);

  // qkv = xn @ wqkv + bqkv
  k_gemm_m<0><<<dim3(12, 90), 256, 0, stream>>>(
      nullptr, xn, wqkv_t, bqkv_f, nullptr, qkv, NTOK, 1536, 512);

  // qkv_p = pooled @ wqkv + bqkv -> bf16 rows appended after qkv
  k_gemm_small<<<dim3(6, 32), 256, 0, stream>>>(dflag, pooled, wqkv, bqkv, qkvpb);

  // MFMA flash attention: 256 blocks (1/CU), 12 waves, 192 queries per block
  k_attn_m<<<dim3(32, 2, NH_), 768, 0, stream>>>(qkv, ksrc, ao);

  // x2 = x + ao @ wproj + bproj
  k_gemm_m<1><<<dim3(4, 90), 256, 0, stream>>>(
      dflag, ao, wproj_t, bproj_f, x, x2, NTOK, 512, 512);

  // LN2 -> y
  k_ln<<<NTOK, 256, 0, stream>>>(dflag, 1, x2, g2, be2, y);

  // h1 = y @ w1 + bf1
  k_gemm_m<0><<<dim3(16, 90), 256, 0, stream>>>(
      nullptr, y, w1_t, bf1_f, nullptr, h1, NTOK, FFN_, 512);

  // T2T fold + normalize
  k_fold<<<(16 * 40 * 60 * 108) / 256, 256, 0, stream>>>(h1, hf);

  // T2T unfold + GELU (in place into buf2)
  k_unfold_gelu<<<(NTOK * FFN_) / 256, 256, 0, stream>>>(hf, h1);

  // out = x2 + gelu_h @ w2 + bf2
  k_gemm_m<2><<<dim3(4, 90), 256, 0, stream>>>(
      dflag, h1, w2_t, bf2_f, x2, d_out, NTOK, 512, FFN_);
}

// Round 10
// 535.805 us; speedup vs baseline: 1.2171x; 1.0133x over previous
//
#include <hip/hip_runtime.h>
#include <hip/hip_bf16.h>
#include <math.h>

typedef __hip_bfloat16 bf16;
typedef __attribute__((ext_vector_type(8))) short bf16x8;
typedef __attribute__((ext_vector_type(4))) float f32x4;

#define DEVI __device__ __forceinline__

// ---------- constants ----------
#define C_ 512
#define NH_ 4
#define NTOK 11520          // B*T*H*W
#define NKEY 1680           // 360 local + 960 rolled + 360 pooled
#define NRK 120
#define FFN_ 1960
#define ZROW (NTOK + 256)   // zeroed key row for invalid slots

// ---------- helpers ----------
DEVI float ldf(const bf16* p) { return __bfloat162float(*p); }
DEVI float ldf(const float* p) { return *p; }
DEVI void stw(bf16* p, float v) { *p = __float2bfloat16(v); }
DEVI void stw(float* p, float v) { *p = v; }
DEVI unsigned short f2bs(float f) { bf16 h = __float2bfloat16(f); return *(unsigned short*)&h; }

// dtype-dispatched scalar load: DT=0 bf16, DT=1 f32
template <int DT> DEVI float ldw(const void* p, size_t i) {
  if (DT == 0) return __bfloat162float(((const bf16*)p)[i]);
  else         return ((const float*)p)[i];
}

// async global->LDS, 16B per lane; lptr is wave-uniform base (HW adds lane*16)
DEVI void gload_lds16(const void* g, void* l) {
  __builtin_amdgcn_global_load_lds(
      (const __attribute__((address_space(1))) void*)g,
      (__attribute__((address_space(3))) void*)l, 16, 0, 0);
}

// ---------- K_init: dtype detect + valid-index table + zero-row ----------
__global__ void k_init(const void* __restrict__ g1, int* __restrict__ flag,
                       int* __restrict__ table, bf16* __restrict__ zp) {
  if (blockIdx.x == 0) {
    if (threadIdx.x == 0) {
      const unsigned short* p = (const unsigned short*)g1;
      *flag = (p[0] == 0x3F80u) ? 0 : 1;
      int cnt = 0;
      for (int pq = 0; pq < 4; pq++)
        for (int wi = 0; wi < 5; wi++)
          for (int wj = 0; wj < 9; wj++) {
            bool invalid;
            if (pq == 0)      invalid = (wi < 3) && (wj < 5);
            else if (pq == 1) invalid = (wi < 3) && (wj >= 4);
            else if (pq == 2) invalid = (wi >= 2) && (wj < 5);
            else              invalid = (wi >= 2) && (wj >= 4);
            if (!invalid) table[cnt++] = pq * 45 + wi * 9 + wj;
          }
    }
  } else {
    zp[(blockIdx.x - 1) * 256 + threadIdx.x] = __float2bfloat16(0.f);
  }
}

// ---------- K0b: per-window key-source table ksrc[32][1680] ----------
// values: token row (<NTOK) for local/rolled, NTOK+pidx for pooled, -1 invalid
__global__ void k_ksrc(const int* __restrict__ vtab, int* __restrict__ ksrc) {
  int idx = blockIdx.x * 256 + threadIdx.x;
  if (idx >= 32 * NKEY) return;
  int w = idx / NKEY, j = idx % NKEY;
  int b = w >> 4, nh = (w >> 2) & 3, nw = w & 3;
  int val;
  if (j < 360) {
    int t = j / 45, pos = j % 45, wi = pos / 9, wj2 = pos % 9;
    val = ((b * 8 + t) * 20 + nh * 5 + wi) * 36 + nw * 9 + wj2;
  } else if (j < 1320) {
    int jj = j - 360;
    int t = jj / 120, r = jj % 120;
    int id = vtab[r];
    int p = id / 45, pos = id % 45, wi = pos / 9, wj2 = pos % 9;
    int sh = (p < 2) ? -2 : 2;
    int sw = (p & 1) ? 4 : -4;
    int hh = nh * 5 + wi - sh;
    if (hh < 0) hh += 20; else if (hh >= 20) hh -= 20;
    int ww2 = nw * 9 + wj2 - sw;
    if (ww2 < 0) ww2 += 36; else if (ww2 >= 36) ww2 -= 36;
    val = ((b * 8 + t) * 20 + hh) * 36 + ww2;
  } else {
    int jj = j - 1320;
    int t = jj / 45, kidx = jj % 45, ki = kidx / 9, kj = kidx % 9;
    int snh = nh + ki - 2, snw = nw + kj - 4;
    if (snh < 0 || snh >= 4 || snw < 0 || snw >= 4) val = -1;
    else val = NTOK + (b * 8 + t) * 16 + snh * 4 + snw;
  }
  ksrc[idx] = val;
}

// ---------- weight convert+transpose (LDS-tiled, both sides coalesced) ----------
// out[n][k] = in[k][n], bf16, zero-pad n>=N.
template <int DT>
DEVI void wcvt_body(const void* in, bf16* out, int K, int N, int Npad,
                    int n0, int k0) {
  __shared__ float t[64][65];
  const int tx = threadIdx.x & 63, tg = threadIdx.x >> 6;
#pragma unroll
  for (int r = 0; r < 16; r++) {
    int k = k0 + r * 4 + tg;
    int nn = n0 + tx;
    float v = (k < K && nn < N) ? ldw<DT>(in, (size_t)k * N + nn) : 0.f;
    t[r * 4 + tg][tx] = v;
  }
  __syncthreads();
#pragma unroll
  for (int r = 0; r < 16; r++) {
    int nn = n0 + r * 4 + tg;
    int k = k0 + tx;
    if (nn < Npad && k < K)
      out[(size_t)nn * K + k] = __float2bfloat16(t[tx][r * 4 + tg]);
  }
}
// all four weights in one launch; 760 blocks total, block-range dispatch
__global__ void k_wcvt4(const int* __restrict__ dflag,
                        const void* __restrict__ i0, bf16* __restrict__ o0,
                        const void* __restrict__ i1, bf16* __restrict__ o1,
                        const void* __restrict__ i2, bf16* __restrict__ o2,
                        const void* __restrict__ i3, bf16* __restrict__ o3) {
  int b = blockIdx.x;
  const void* in; bf16* out; int K, N, Npad, nb, lb;
  if (b < 192)      { in = i0; out = o0; K = 512;  N = 1536; Npad = 1536; nb = 24; lb = b; }
  else if (b < 256) { in = i1; out = o1; K = 512;  N = 512;  Npad = 512;  nb = 8;  lb = b - 192; }
  else if (b < 512) { in = i2; out = o2; K = 512;  N = FFN_; Npad = 2048; nb = 32; lb = b - 256; }
  else              { in = i3; out = o3; K = FFN_; N = 512;  Npad = 512;  nb = 8;  lb = b - 512; }
  int n0 = (lb % nb) * 64, k0 = (lb / nb) * 64;
  if (*dflag == 0) wcvt_body<0>(in, out, K, N, Npad, n0, k0);
  else             wcvt_body<1>(in, out, K, N, Npad, n0, k0);
}

// ---------- bias convert -> f32 (all four biases in one launch) ----------
__global__ void k_bcvt4(const int* __restrict__ dflag,
                        const void* __restrict__ b0, float* __restrict__ o0,
                        const void* __restrict__ b1, float* __restrict__ o1,
                        const void* __restrict__ b2, float* __restrict__ o2,
                        const void* __restrict__ b3, float* __restrict__ o3) {
  int dt = *dflag;
  int bx = blockIdx.x;
  const void* src; float* dst; int n, i;
  if (bx < 6)       { src = b0; dst = o0; n = 1536; i = bx * 256 + threadIdx.x; }
  else if (bx < 8)  { src = b1; dst = o1; n = 512;  i = (bx - 6) * 256 + threadIdx.x; }
  else if (bx < 16) { src = b2; dst = o2; n = FFN_; i = (bx - 8) * 256 + threadIdx.x; }
  else              { src = b3; dst = o3; n = 512;  i = (bx - 16) * 256 + threadIdx.x; }
  if (i < n) dst[i] = (dt == 0) ? ldw<0>(src, i) : ldw<1>(src, i);
}

// ---------- LayerNorm over C=512 ----------
template <int DTIN, int DTP>
DEVI void ln_body(const void* xin, const void* g, const void* be, bf16* out) {
  const int tok = blockIdx.x;
  const int tid = threadIdx.x;
  const size_t base = (size_t)tok * C_;
  float v0 = ldw<DTIN>(xin, base + tid);
  float v1 = ldw<DTIN>(xin, base + tid + 256);
  float s = v0 + v1, ss = v0 * v0 + v1 * v1;
#pragma unroll
  for (int o = 32; o; o >>= 1) { s += __shfl_xor(s, o); ss += __shfl_xor(ss, o); }
  __shared__ float sh[10];
  const int lane = tid & 63, wv = tid >> 6;
  if (lane == 0) { sh[wv] = s; sh[4 + wv] = ss; }
  __syncthreads();
  if (tid == 0) {
    float a = sh[0] + sh[1] + sh[2] + sh[3];
    float q = sh[4] + sh[5] + sh[6] + sh[7];
    float mu = a * (1.0f / C_);
    float var = q * (1.0f / C_) - mu * mu;
    sh[8] = mu; sh[9] = rsqrtf(fmaxf(var, 0.f) + 1e-5f);
  }
  __syncthreads();
  float mu = sh[8], inv = sh[9];
  stw(out + base + tid,
      (v0 - mu) * inv * ldw<DTP>(g, tid) + ldw<DTP>(be, tid));
  stw(out + base + tid + 256,
      (v1 - mu) * inv * ldw<DTP>(g, tid + 256) + ldw<DTP>(be, tid + 256));
}
// mode 0: input dtype follows dflag (LN1); mode 1: input always f32 (LN2)
__global__ void k_ln(const int* __restrict__ dflag, int mode,
                     const void* __restrict__ xin, const void* __restrict__ g,
                     const void* __restrict__ be, bf16* __restrict__ out) {
  int dt = *dflag;
  if (mode == 0) {
    if (dt == 0) ln_body<0, 0>(xin, g, be, out);
    else         ln_body<1, 1>(xin, g, be, out);
  } else {
    if (dt == 0) ln_body<1, 0>(xin, g, be, out);
    else         ln_body<1, 1>(xin, g, be, out);
  }
}

// ---------- window pooling ----------
template <int DT>
DEVI void pool_body(const bf16* xn, const void* wpool, const void* bpool,
                    float* pooled) {
  int idx = blockIdx.x * blockDim.x + threadIdx.x;
  if (idx >= 256 * C_) return;
  int c = idx & (C_ - 1);
  int fw = idx >> 9;
  int nw = fw & 3, nh = (fw >> 2) & 3;
  int bt = fw >> 4;
  float acc = ldw<DT>(bpool, 0);
  for (int wi = 0; wi < 5; wi++) {
    int hh = nh * 5 + wi;
    const bf16* base = xn + (((size_t)(bt * 20 + hh)) * 36 + nw * 9) * C_ + c;
    for (int wj = 0; wj < 9; wj++)
      acc += __bfloat162float(base[(size_t)wj * C_]) * ldw<DT>(wpool, wi * 9 + wj);
  }
  pooled[idx] = acc;
}
__global__ void k_pool(const int* __restrict__ dflag, const bf16* __restrict__ xn,
                       const void* __restrict__ wpool, const void* __restrict__ bpool,
                       float* __restrict__ pooled) {
  if (*dflag == 0) pool_body<0>(xn, wpool, bpool, pooled);
  else             pool_body<1>(xn, wpool, bpool, pooled);
}

// ---------- small GEMM pooled(f32) @ wqkv + bqkv -> qkvp_b (bf16, stride 1536) ----------
template <int DT>
DEVI void gemm_small_body(const float* A, const void* Bw, const void* bias,
                          bf16* Cc) {
  __shared__ float As[8][512];
  const int n = blockIdx.x * 256 + threadIdx.x;
  const int m0 = blockIdx.y * 8;
  for (int i = threadIdx.x; i < 8 * 512; i += 256)
    As[i >> 9][i & 511] = A[(size_t)(m0 + (i >> 9)) * 512 + (i & 511)];
  __syncthreads();
  float acc[8];
  float bv = ldw<DT>(bias, n);
#pragma unroll
  for (int mm = 0; mm < 8; mm++) acc[mm] = bv;
  for (int k = 0; k < 512; k++) {
    float b = ldw<DT>(Bw, (size_t)k * 1536 + n);
#pragma unroll
    for (int mm = 0; mm < 8; mm++) acc[mm] += As[mm][k] * b;
  }
#pragma unroll
  for (int mm = 0; mm < 8; mm++)
    Cc[(size_t)(m0 + mm) * 1536 + n] = __float2bfloat16(acc[mm]);
}
__global__ void k_gemm_small(const int* __restrict__ dflag, const float* __restrict__ A,
                             const void* __restrict__ Bw, const void* __restrict__ bias,
                             bf16* __restrict__ Cc) {
  if (*dflag == 0) gemm_small_body<0>(A, Bw, bias, Cc);
  else             gemm_small_body<1>(A, Bw, bias, Cc);
}

// ---------- MFMA GEMM 128x128 (proven path, proj/w2) ----------
// BK=64 as two [128][32] chunks; XCD chunked swizzle (grids here have nwg%8==0).
// RES=1: out f32, resid dtype = *dflag.  RES=2: resid f32, out dtype = *dflag.
template <int RES>
__global__ __launch_bounds__(256) void k_gemm_m(const int* __restrict__ dflag,
                                                const bf16* __restrict__ A,
                                                const bf16* __restrict__ Bt,
                                                const float* __restrict__ bias,
                                                const void* __restrict__ resid,
                                                void* __restrict__ out,
                                                int M, int N, int K) {
  const int dt = dflag ? *dflag : 0;
  __shared__ __align__(16) unsigned short As[2][128 * 32];
  __shared__ __align__(16) unsigned short Bs[2][128 * 32];
  const int tid = threadIdx.x;
  const int lane = tid & 63, wid = tid >> 6;
  const int r15 = lane & 15, quad = lane >> 4;
  const int wm = wid >> 1, wn = wid & 1;
  const int nbx = gridDim.x;
  const int lin = blockIdx.x + nbx * blockIdx.y;
  const int cpx = (nbx * gridDim.y) >> 3;
  const int swz = (lin & 7) * cpx + (lin >> 3);
  const int m0 = (swz / nbx) * 128, n0 = (swz % nbx) * 128;

  f32x4 acc[4][4];
#pragma unroll
  for (int i = 0; i < 4; i++)
#pragma unroll
    for (int j = 0; j < 4; j++)
#pragma unroll
      for (int e = 0; e < 4; e++) acc[i][j][e] = 0.f;

  const int lrow = lane >> 2, lcol = (lane & 3) * 8;

  for (int k0 = 0; k0 < K; k0 += 64) {
    int rem = K - k0;
    if (rem >= 64) {
      const bf16* ga = A + (size_t)(m0 + wid * 32 + lrow) * K + k0 + lcol;
      gload_lds16(ga, &As[0][wid * 1024]);
      gload_lds16(ga + (size_t)16 * K, &As[0][wid * 1024 + 512]);
      gload_lds16(ga + 32, &As[1][wid * 1024]);
      gload_lds16(ga + (size_t)16 * K + 32, &As[1][wid * 1024 + 512]);
      const bf16* gb = Bt + (size_t)(n0 + wid * 32 + lrow) * K + k0 + lcol;
      gload_lds16(gb, &Bs[0][wid * 1024]);
      gload_lds16(gb + (size_t)16 * K, &Bs[0][wid * 1024 + 512]);
      gload_lds16(gb + 32, &Bs[1][wid * 1024]);
      gload_lds16(gb + (size_t)16 * K + 32, &Bs[1][wid * 1024 + 512]);
    } else {
      // tail (rem multiple of 8, < 64): 32 rows x 64 cols per pass, 4 passes
      int r = tid >> 3, c = (tid & 7) * 8;
      uint4 z = make_uint4(0, 0, 0, 0);
      int h = c >> 5, cc = c & 31;
#pragma unroll
      for (int p = 0; p < 4; p++) {
        int row = r + p * 32;
        uint4 av = z, bv = z;
        if (c < rem) {
          av = *(const uint4*)(A + (size_t)(m0 + row) * K + k0 + c);
          bv = *(const uint4*)(Bt + (size_t)(n0 + row) * K + k0 + c);
        }
        *(uint4*)&As[h][row * 32 + cc] = av;
        *(uint4*)&Bs[h][row * 32 + cc] = bv;
      }
    }
    __syncthreads();

#pragma unroll
    for (int h = 0; h < 2; h++) {
      bf16x8 af[4], bfr[4];
#pragma unroll
      for (int mf = 0; mf < 4; mf++)
        af[mf] = *(const bf16x8*)&As[h][(wm * 64 + mf * 16 + r15) * 32 + quad * 8];
#pragma unroll
      for (int nf = 0; nf < 4; nf++)
        bfr[nf] = *(const bf16x8*)&Bs[h][(wn * 64 + nf * 16 + r15) * 32 + quad * 8];
#pragma unroll
      for (int mf = 0; mf < 4; mf++)
#pragma unroll
        for (int nf = 0; nf < 4; nf++)
          acc[mf][nf] = __builtin_amdgcn_mfma_f32_16x16x32_bf16(af[mf], bfr[nf],
                                                                acc[mf][nf], 0, 0, 0);
    }
    __syncthreads();
  }

#pragma unroll
  for (int nf = 0; nf < 4; nf++) {
    int n = n0 + wn * 64 + nf * 16 + r15;
    if (n >= N) continue;
    float bv = bias[n];
#pragma unroll
    for (int mf = 0; mf < 4; mf++) {
      int mb = m0 + wm * 64 + mf * 16 + quad * 4;
#pragma unroll
      for (int e = 0; e < 4; e++) {
        size_t off = (size_t)(mb + e) * N + n;
        float v = acc[mf][nf][e] + bv;
        if (RES == 1) v += (dt == 0) ? ldw<0>(resid, off) : ldw<1>(resid, off);
        else if (RES == 2) v += ((const float*)resid)[off];
        if (RES == 1) ((float*)out)[off] = v;
        else {
          if (dt == 0) ((bf16*)out)[off] = __float2bfloat16(v);
          else         ((float*)out)[off] = v;
        }
      }
    }
  }
}

// ---------- MFMA GEMM 256x128, 512 thr / 8 waves (qkv & w1: RES=0, K%64==0) ----------
// Per-block FLOPs 2x at same barrier count -> drains+epilogue per FLOP halve.
// Per-wave compute identical to 128x128 kernel (64x64 sub-band, acc[4][4]).
// Bijective XCD swizzle (m204) since nwg%8 != 0 (540/720).
__global__ __launch_bounds__(512) void k_gemm_m2(const bf16* __restrict__ A,
                                                 const bf16* __restrict__ Bt,
                                                 const float* __restrict__ bias,
                                                 bf16* __restrict__ out,
                                                 int M, int N, int K) {
  __shared__ __align__(16) unsigned short As[2][256 * 32];
  __shared__ __align__(16) unsigned short Bs[2][128 * 32];
  const int tid = threadIdx.x;
  const int lane = tid & 63, wid = tid >> 6;   // 0..7
  const int r15 = lane & 15, quad = lane >> 4;
  const int wm = wid >> 1, wn = wid & 1;       // wm 0..3 (64-row band), wn 0..1
  // bijective XCD swizzle (works for any nwg)
  const int nbx = gridDim.x;
  const int nwg = nbx * gridDim.y;
  const int lin = blockIdx.x + nbx * blockIdx.y;
  const int q8 = nwg >> 3, r8 = nwg & 7;
  const int xcd = lin & 7, ii = lin >> 3;
  const int swz = (xcd < r8 ? xcd * (q8 + 1) : r8 * (q8 + 1) + (xcd - r8) * q8) + ii;
  const int m0 = (swz / nbx) * 256, n0 = (swz % nbx) * 128;

  f32x4 acc[4][4];
#pragma unroll
  for (int i = 0; i < 4; i++)
#pragma unroll
    for (int j = 0; j < 4; j++)
#pragma unroll
      for (int e = 0; e < 4; e++) acc[i][j][e] = 0.f;

  const int lrow = lane >> 2, lcol = (lane & 3) * 8;

  for (int k0 = 0; k0 < K; k0 += 64) {
    // A: each wave stages 32 rows (2 gloads x 2 chunks); B: 16 rows (1 x 2)
    const bf16* ga = A + (size_t)(m0 + wid * 32 + lrow) * K + k0 + lcol;
    gload_lds16(ga, &As[0][wid * 1024]);
    gload_lds16(ga + (size_t)16 * K, &As[0][wid * 1024 + 512]);
    gload_lds16(ga + 32, &As[1][wid * 1024]);
    gload_lds16(ga + (size_t)16 * K + 32, &As[1][wid * 1024 + 512]);
    const bf16* gb = Bt + (size_t)(n0 + wid * 16 + lrow) * K + k0 + lcol;
    gload_lds16(gb, &Bs[0][wid * 512]);
    gload_lds16(gb + 32, &Bs[1][wid * 512]);
    __syncthreads();

#pragma unroll
    for (int h = 0; h < 2; h++) {
      bf16x8 af[4], bfr[4];
#pragma unroll
      for (int mf = 0; mf < 4; mf++)
        af[mf] = *(const bf16x8*)&As[h][(wm * 64 + mf * 16 + r15) * 32 + quad * 8];
#pragma unroll
      for (int nf = 0; nf < 4; nf++)
        bfr[nf] = *(const bf16x8*)&Bs[h][(wn * 64 + nf * 16 + r15) * 32 + quad * 8];
#pragma unroll
      for (int mf = 0; mf < 4; mf++)
#pragma unroll
        for (int nf = 0; nf < 4; nf++)
          acc[mf][nf] = __builtin_amdgcn_mfma_f32_16x16x32_bf16(af[mf], bfr[nf],
                                                                acc[mf][nf], 0, 0, 0);
    }
    __syncthreads();
  }

#pragma unroll
  for (int nf = 0; nf < 4; nf++) {
    int n = n0 + wn * 64 + nf * 16 + r15;
    if (n >= N) continue;
    float bv = bias[n];
#pragma unroll
    for (int mf = 0; mf < 4; mf++) {
      int mb = m0 + wm * 64 + mf * 16 + quad * 4;
#pragma unroll
      for (int e = 0; e < 4; e++) {
        size_t off = (size_t)(mb + e) * N + n;
        out[off] = __float2bfloat16(acc[mf][nf][e] + bv);
      }
    }
  }
}

// ---------- MFMA flash attention (768 thr, 12 waves, K/V double-buffered) ----------
// grid: (32 windows, 2 qtiles, 4 heads) = 256 blocks (1 per CU)
// Branch-free staging via uniform bf16 key rows; named-scalar staging regs
// (promote-alloca hazard); defer-max softmax (THR=8); lazy per-lane l partial.
#define KT 64
#define KPAD 136
#define VPAD 72
__global__ __launch_bounds__(768) void k_attn_m(const bf16* __restrict__ qkv,
                                                const int* __restrict__ ksrc,
                                                bf16* __restrict__ ao) {
  __shared__ int ks_l[NKEY];
  __shared__ __align__(16) unsigned short ktl[2][KT * KPAD];    // K [key][dim]
  __shared__ __align__(16) unsigned short vtl[2][128 * VPAD];   // V^T [dim][key]
  __shared__ __align__(16) unsigned short ptl[12 * 16 * VPAD];  // P per wave [q][key]
  __shared__ float maskv[2][KT];

  const int tid = threadIdx.x;
  const int lane = tid & 63, wid = tid >> 6;   // wid 0..11
  const int r15 = lane & 15, quad = lane >> 4;
  const int w = blockIdx.x, qt = blockIdx.y, n = blockIdx.z;
  const int b = w >> 4, nh = (w >> 2) & 3, nw = w & 3;
  const unsigned short* qkvs = (const unsigned short*)qkv;

  for (int j = tid; j < NKEY; j += 768) ks_l[j] = ksrc[w * NKEY + j];

  // Q A-fragments (16 queries per wave), clamped for padding
  bf16x8 qf[4];
  {
    int qw = qt * 192 + wid * 16 + r15;
    int qc2 = qw < 360 ? qw : 359;
    int t = qc2 / 45, pos = qc2 % 45, wi = pos / 9, wj = pos % 9;
    int tok = ((b * 8 + t) * 20 + nh * 5 + wi) * 36 + nw * 9 + wj;
    const unsigned short* qp = qkvs + (size_t)tok * 1536 + n * 128 + quad * 8;
#pragma unroll
    for (int c = 0; c < 4; c++)
      qf[c] = *(const bf16x8*)(qp + c * 32);
  }

  f32x4 of[8];
#pragma unroll
  for (int nt = 0; nt < 8; nt++)
#pragma unroll
    for (int e = 0; e < 4; e++) of[nt][e] = 0.f;
  float m_[4], l_[4];   // l_ is a PER-LANE partial sum (reduced once at the end)
#pragma unroll
  for (int e = 0; e < 4; e++) { m_[e] = -1e30f; l_[e] = 0.f; }

  unsigned short* ptw = &ptl[wid * 16 * VPAD];

  // staging roles
  const bool isK = (wid < 4);
  const int kr = tid >> 2, kp = tid & 3;   // K role (tid < 256)
  const int vr = lane, vp8 = wid - 4;      // V role (wid >= 4)
  // named staging registers (NOT arrays -> guaranteed VGPRs)
  uint4 k0, k1, k2, k3, v0, v1;
  float mreg = -30000.f;
  // wave-invariant base offsets
  const unsigned short* kbase = qkvs + 512 + n * 128 + kp * 32;
  const unsigned short* vbase = qkvs + 1024 + n * 128 + vp8 * 16;

  auto load_tile = [&](int j0) {
    int cnt = NKEY - j0; if (cnt > KT) cnt = KT;
    if (isK) {
      int s0 = (kr < cnt) ? ks_l[j0 + kr] : -1;
      mreg = (s0 < 0) ? -30000.f : 0.f;
      int row = (s0 < 0) ? ZROW : s0;
      const uint4* kq = (const uint4*)(kbase + (size_t)row * 1536);
      k0 = kq[0]; k1 = kq[1]; k2 = kq[2]; k3 = kq[3];
    } else {
      int s1 = (vr < cnt) ? ks_l[j0 + vr] : -1;
      int row = (s1 < 0) ? ZROW : s1;
      const uint4* vq = (const uint4*)(vbase + (size_t)row * 1536);
      v0 = vq[0]; v1 = vq[1];
    }
  };

  auto store_tile = [&](int buf) {
    if (isK) {
      if (kp == 0) maskv[buf][kr] = mreg;
      unsigned short* kb = &ktl[buf][kr * KPAD + kp * 32];
      *(uint4*)&kb[0]  = k0;
      *(uint4*)&kb[8]  = k1;
      *(uint4*)&kb[16] = k2;
      *(uint4*)&kb[24] = k3;
    } else {
      unsigned short* vb = &vtl[buf][0];
      int d0 = vp8 * 16;
      vb[(d0 + 0) * VPAD + vr]  = (unsigned short)(v0.x & 0xFFFFu);
      vb[(d0 + 1) * VPAD + vr]  = (unsigned short)(v0.x >> 16);
      vb[(d0 + 2) * VPAD + vr]  = (unsigned short)(v0.y & 0xFFFFu);
      vb[(d0 + 3) * VPAD + vr]  = (unsigned short)(v0.y >> 16);
      vb[(d0 + 4) * VPAD + vr]  = (unsigned short)(v0.z & 0xFFFFu);
      vb[(d0 + 5) * VPAD + vr]  = (unsigned short)(v0.z >> 16);
      vb[(d0 + 6) * VPAD + vr]  = (unsigned short)(v0.w & 0xFFFFu);
      vb[(d0 + 7) * VPAD + vr]  = (unsigned short)(v0.w >> 16);
      vb[(d0 + 8) * VPAD + vr]  = (unsigned short)(v1.x & 0xFFFFu);
      vb[(d0 + 9) * VPAD + vr]  = (unsigned short)(v1.x >> 16);
      vb[(d0 + 10) * VPAD + vr] = (unsigned short)(v1.y & 0xFFFFu);
      vb[(d0 + 11) * VPAD + vr] = (unsigned short)(v1.y >> 16);
      vb[(d0 + 12) * VPAD + vr] = (unsigned short)(v1.z & 0xFFFFu);
      vb[(d0 + 13) * VPAD + vr] = (unsigned short)(v1.z >> 16);
      vb[(d0 + 14) * VPAD + vr] = (unsigned short)(v1.w & 0xFFFFu);
      vb[(d0 + 15) * VPAD + vr] = (unsigned short)(v1.w >> 16);
    }
  };

  __syncthreads();        // ks_l ready
  load_tile(0);
  store_tile(0);
  load_tile(KT);          // prefetch tile 1 into regs (NKEY > KT always)
  __syncthreads();        // buf 0 ready

  int cur = 0, j0 = 0;
  while (true) {
    int nxt = j0 + KT;
    if (nxt < NKEY) {
      store_tile(cur ^ 1);                        // regs (tile nxt) -> idle buffer
      if (nxt + KT < NKEY) load_tile(nxt + KT);   // prefetch tile nxt+KT
    }

    const unsigned short* ktc = &ktl[cur][0];
    const unsigned short* vtc = &vtl[cur][0];
    const float* mkc = maskv[cur];

    // ---- QK^T ----
    f32x4 sf[4];
#pragma unroll
    for (int ft = 0; ft < 4; ft++)
#pragma unroll
      for (int e = 0; e < 4; e++) sf[ft][e] = 0.f;
#pragma unroll
    for (int kc = 0; kc < 4; kc++) {
      bf16x8 a = qf[kc];
#pragma unroll
      for (int ft = 0; ft < 4; ft++) {
        bf16x8 bb = *(const bf16x8*)&ktc[(ft * 16 + r15) * KPAD + kc * 32 + quad * 8];
        sf[ft] = __builtin_amdgcn_mfma_f32_16x16x32_bf16(a, bb, sf[ft], 0, 0, 0);
      }
    }
    const float scl = 0.088388347648318447f;
#pragma unroll
    for (int ft = 0; ft < 4; ft++) {
      float mk = mkc[ft * 16 + r15];
#pragma unroll
      for (int e = 0; e < 4; e++) sf[ft][e] = sf[ft][e] * scl + mk;
    }
    // ---- online softmax (defer-max THR=8; lazy per-lane l partial) ----
    float tm[4];
#pragma unroll
    for (int e = 0; e < 4; e++) {
      float v = fmaxf(fmaxf(sf[0][e], sf[1][e]), fmaxf(sf[2][e], sf[3][e]));
#pragma unroll
      for (int o = 1; o < 16; o <<= 1) v = fmaxf(v, __shfl_xor(v, o));
      tm[e] = v;
    }
    bool grow = (tm[0] > m_[0] + 8.f) | (tm[1] > m_[1] + 8.f) |
                (tm[2] > m_[2] + 8.f) | (tm[3] > m_[3] + 8.f);
    if (__any(grow)) {
#pragma unroll
      for (int e = 0; e < 4; e++) {
        float mn = fmaxf(m_[e], tm[e]);
        float alpha = __expf(m_[e] - mn);
        m_[e] = mn;
        float rs = 0.f;
#pragma unroll
        for (int ft = 0; ft < 4; ft++) {
          float pv = __expf(sf[ft][e] - mn);
          rs += pv;
          ptw[(quad * 4 + e) * VPAD + ft * 16 + r15] = f2bs(pv);
        }
        l_[e] = l_[e] * alpha + rs;
#pragma unroll
        for (int nt = 0; nt < 8; nt++) of[nt][e] *= alpha;
      }
    } else {
#pragma unroll
      for (int e = 0; e < 4; e++) {
        float rs = 0.f;
#pragma unroll
        for (int ft = 0; ft < 4; ft++) {
          float pv = __expf(sf[ft][e] - m_[e]);
          rs += pv;
          ptw[(quad * 4 + e) * VPAD + ft * 16 + r15] = f2bs(pv);
        }
        l_[e] += rs;
      }
    }
    // ---- PV ----
#pragma unroll
    for (int kc = 0; kc < 2; kc++) {
      bf16x8 pa = *(const bf16x8*)&ptw[r15 * VPAD + kc * 32 + quad * 8];
#pragma unroll
      for (int nt = 0; nt < 8; nt++) {
        bf16x8 vb = *(const bf16x8*)&vtc[(nt * 16 + r15) * VPAD + kc * 32 + quad * 8];
        of[nt] = __builtin_amdgcn_mfma_f32_16x16x32_bf16(pa, vb, of[nt], 0, 0, 0);
      }
    }

    if (nxt >= NKEY) break;
    __syncthreads();       // all waves done reading buf cur; buf cur^1 fully stored
    cur ^= 1; j0 = nxt;
  }

  // ---- final l reduction + normalize + store ----
#pragma unroll
  for (int e = 0; e < 4; e++) {
#pragma unroll
    for (int o = 1; o < 16; o <<= 1) l_[e] += __shfl_xor(l_[e], o);
  }
#pragma unroll
  for (int e = 0; e < 4; e++) {
    int qw = qt * 192 + wid * 16 + quad * 4 + e;
    if (qw >= 360) continue;
    float inv = 1.0f / l_[e];
    int t = qw / 45, pos = qw % 45, wi = pos / 9, wj = pos % 9;
    int tok = ((b * 8 + t) * 20 + nh * 5 + wi) * 36 + nw * 9 + wj;
    bf16* op = ao + (size_t)tok * 512 + n * 128 + r15;
#pragma unroll
    for (int nt = 0; nt < 8; nt++)
      stw(op + nt * 16, of[nt][e] * inv);
  }
}

// ---------- T2T fold + normalize (scalar, coalesced reads) ----------
__global__ void k_fold(const bf16* __restrict__ h1, float* __restrict__ hf) {
  int idx = blockIdx.x * 256 + threadIdx.x;
  if (idx >= 16 * 40 * 60 * 108) return;
  int x = idx % 108;
  int tmp = idx / 108;
  int y = tmp % 60; tmp /= 60;
  int c = tmp % 40;
  int bt = tmp / 40;
  float sum = 0.f;
  int cnt = 0;
  for (int ki = y % 3; ki < 7; ki += 3) {
    int num = y + 3 - ki;
    if (num < 0) continue;
    int oh = num / 3;
    if (oh >= 20) continue;
    for (int kj = x % 3; kj < 7; kj += 3) {
      int num2 = x + 3 - kj;
      if (num2 < 0) continue;
      int ow = num2 / 3;
      if (ow >= 36) continue;
      sum += __bfloat162float(
          h1[(size_t)(bt * 720 + oh * 36 + ow) * FFN_ + c * 49 + ki * 7 + kj]);
      cnt++;
    }
  }
  hf[idx] = sum / (float)cnt;
}

// ---------- T2T unfold + GELU (scalar, coalesced reads) ----------
__global__ void k_unfold_gelu(const float* __restrict__ hf, bf16* __restrict__ h2) {
  int idx = blockIdx.x * 256 + threadIdx.x;
  if (idx >= NTOK * FFN_) return;
  int f = idx % FFN_;
  int token = idx / FFN_;
  int c = f / 49, k = f % 49, ki = k / 7, kj = k % 7;
  int bt = token / 720, vec = token % 720;
  int oh = vec / 36, ow = vec % 36;
  int y = oh * 3 + ki - 3, x = ow * 3 + kj - 3;
  float v = 0.f;
  if (y >= 0 && y < 60 && x >= 0 && x < 108)
    v = hf[((size_t)(bt * 40 + c) * 60 + y) * 108 + x];
  float g = 0.5f * v * (1.0f + erff(v * 0.70710678118654752f));
  stw(h2 + idx, g);
}

// ---------- launcher ----------
extern "C" void kernel_launch(void* const* d_in, const int* in_sizes, int n_in,
                              void* d_out, int out_size, void* d_ws, size_t ws_size,
                              hipStream_t stream) {
  (void)in_sizes; (void)n_in; (void)out_size; (void)ws_size;
  const void* x     = d_in[0];
  const void* g1    = d_in[1];
  const void* be1   = d_in[2];
  const void* wqkv  = d_in[3];
  const void* bqkv  = d_in[4];
  const void* wproj = d_in[5];
  const void* bproj = d_in[6];
  const void* wpool = d_in[7];
  const void* bpool = d_in[8];
  const void* g2    = d_in[9];
  const void* be2   = d_in[10];
  const void* w1    = d_in[11];
  const void* bf1   = d_in[12];
  const void* w2    = d_in[13];
  const void* bf2   = d_in[14];

  char* ws = (char*)d_ws;
  size_t off = 0;
  auto alloc = [&](size_t bytes) -> void* {
    void* p = ws + off;
    off += (bytes + 255) & ~(size_t)255;
    return p;
  };

  int*   dflag  = (int*)  alloc(256);
  int*   vtab   = (int*)  alloc(NRK * sizeof(int));
  int*   ksrc   = (int*)  alloc((size_t)32 * NKEY * sizeof(int));
  bf16*  buf2   = (bf16*) alloc((size_t)NTOK * FFN_ * 2);   // qkv+qkvp_b -> h1/h2
  float* pooled = (float*)alloc((size_t)256 * C_ * 4);
  float* x2     = (float*)alloc((size_t)NTOK * C_ * 4);
  float* hf     = (float*)alloc((size_t)16 * 40 * 60 * 108 * 4);
  bf16*  wqkv_t = (bf16*) alloc((size_t)1536 * 512 * 2);
  bf16*  wproj_t= (bf16*) alloc((size_t)512 * 512 * 2);
  bf16*  w1_t   = (bf16*) alloc((size_t)2048 * 512 * 2);    // zero-padded 1960->2048
  bf16*  w2_t   = (bf16*) alloc((size_t)512 * FFN_ * 2);
  float* bqkv_f = (float*)alloc(1536 * 4);
  float* bproj_f= (float*)alloc(512 * 4);
  float* bf1_f  = (float*)alloc(FFN_ * 4);
  float* bf2_f  = (float*)alloc(512 * 4);

  bf16* buf1 = (bf16*)d_out;   // xn -> ao -> y scratch (dead before final GEMM)
  bf16* xn = buf1;
  bf16* ao = buf1;
  bf16* y  = buf1;
  bf16* qkv = buf2;
  bf16* h1  = buf2;
  bf16* qkvpb = buf2 + (size_t)NTOK * 1536;   // 257 rows: 256 pooled + 1 zero row

  // detect + prep + zero-row in one launch
  k_init<<<7, 256, 0, stream>>>(g1, dflag, vtab, qkvpb + (size_t)256 * 1536);
  k_ksrc<<<(32 * NKEY) / 256, 256, 0, stream>>>(vtab, ksrc);

  // all weight transposes in one launch; all biases in one launch
  k_wcvt4<<<760, 256, 0, stream>>>(dflag, wqkv, wqkv_t, wproj, wproj_t,
                                   w1, w1_t, w2, w2_t);
  k_bcvt4<<<18, 256, 0, stream>>>(dflag, bqkv, bqkv_f, bproj, bproj_f,
                                  bf1, bf1_f, bf2, bf2_f);

  // LN1
  k_ln<<<NTOK, 256, 0, stream>>>(dflag, 0, x, g1, be1, xn);

  // window pooling
  k_pool<<<512, 256, 0, stream>>>(dflag, xn, wpool, bpool, pooled);

  // qkv = xn @ wqkv + bqkv  (256x128 tile)
  k_gemm_m2<<<dim3(12, 45), 512, 0, stream>>>(
      xn, wqkv_t, bqkv_f, qkv, NTOK, 1536, 512);

  // qkv_p = pooled @ wqkv + bqkv -> bf16 rows appended after qkv
  k_gemm_small<<<dim3(6, 32), 256, 0, stream>>>(dflag, pooled, wqkv, bqkv, qkvpb);

  // MFMA flash attention: 256 blocks (1/CU), 12 waves, 192 queries per block
  k_attn_m<<<dim3(32, 2, NH_), 768, 0, stream>>>(qkv, ksrc, ao);

  // x2 = x + ao @ wproj + bproj
  k_gemm_m<1><<<dim3(4, 90), 256, 0, stream>>>(
      dflag, ao, wproj_t, bproj_f, x, x2, NTOK, 512, 512);

  // LN2 -> y
  k_ln<<<NTOK, 256, 0, stream>>>(dflag, 1, x2, g2, be2, y);

  // h1 = y @ w1 + bf1  (256x128 tile)
  k_gemm_m2<<<dim3(16, 45), 512, 0, stream>>>(
      y, w1_t, bf1_f, h1, NTOK, FFN_, 512);

  // T2T fold + normalize
  k_fold<<<(16 * 40 * 60 * 108) / 256, 256, 0, stream>>>(h1, hf);

  // T2T unfold + GELU (in place into buf2)
  k_unfold_gelu<<<(NTOK * FFN_) / 256, 256, 0, stream>>>(hf, h1);

  // out = x2 + gelu_h @ w2 + bf2
  k_gemm_m<2><<<dim3(4, 90), 256, 0, stream>>>(
      dflag, h1, w2_t, bf2_f, x2, d_out, NTOK, 512, FFN_);
}